// Round 12
// baseline (76.221 us; speedup 1.0000x reference)
//
#include <hip/hip_runtime.h>

using u16 = unsigned short;
using u32 = unsigned int;
using u64 = unsigned long long;

typedef short bf16x8 __attribute__((ext_vector_type(8)));
typedef float f32x4 __attribute__((ext_vector_type(4)));

static constexpr int NB  = 4;     // batch
static constexpr int NN  = 4096;  // nodes
static constexpr int KIN = 256;   // in features
static constexpr int FO  = 128;   // out features
static constexpr int NROW = NB * NN;  // 16384 total rows
static constexpr int NCC = 128;   // chunks per batch
static constexpr int CH  = 32;    // positions per chunk
static constexpr int NGB = NN / 4;    // prefix groups per batch (1024)
static constexpr float SLOPE = 0.01f;

// ---- bf16 helpers (RNE, no NaN inputs) ----
__device__ __forceinline__ u16 f2bf(float f) {
  const u32 u = __float_as_uint(f);
  return (u16)((u + 0x7fffu + ((u >> 16) & 1u)) >> 16);
}
__device__ __forceinline__ float bf2f(u16 h) {
  return __uint_as_float(((u32)h) << 16);
}
__device__ __forceinline__ float dot4(const float4& a, const float4& b) {
  return a.x * b.x + a.y * b.y + a.z * b.z + a.w * b.w;
}

// monotone bijection f32 -> orderable u32 (no NaNs present)
__device__ __forceinline__ u32 f2key(float f) {
  const u32 b = __float_as_uint(f);
  return (b & 0x80000000u) ? ~b : (b | 0x80000000u);
}
__device__ __forceinline__ float key2f(u32 u) {
  const u32 b = (u & 0x80000000u) ? (u ^ 0x80000000u) : ~u;
  return __uint_as_float(b);
}

__device__ __forceinline__ u64 shfl_xor64(u64 v, int m) {
  const u32 lo = __shfl_xor((u32)(v & 0xffffffffu), m, 64);
  const u32 hi = __shfl_xor((u32)(v >> 32), m, 64);
  return ((u64)hi << 32) | (u64)lo;
}
__device__ __forceinline__ void cswap(u64& a, u64& b, bool up) {
  if ((a > b) == up) { const u64 tmp = a; a = b; b = tmp; }
}

// bitonic rounds j = min(k/2,128)..1 for phase k, data in registers.
__device__ __forceinline__ void reg_session(u64 e[4], int t, int k) {
  const int jstart = (k > 256) ? 128 : (k >> 1);
  for (int j = jstart; j >= 4; j >>= 1) {
    const int J = j >> 2;
    const bool up   = ((t & (k >> 2)) == 0);
    const bool lowr = ((t & J) == 0);
#pragma unroll
    for (int r = 0; r < 4; ++r) {
      const u64 o = shfl_xor64(e[r], J);
      const bool less = e[r] < o;              // keys unique (idx tie-break)
      e[r] = ((lowr == up) == less) ? e[r] : o;
    }
  }
  if (k >= 4) {
    const bool up = ((t & (k >> 2)) == 0);
    cswap(e[0], e[2], up); cswap(e[1], e[3], up);
  }
  {
    const bool up0 = (((4 * t)     & k) == 0);
    const bool up1 = (((4 * t + 2) & k) == 0);
    cswap(e[0], e[1], up0); cswap(e[2], e[3], up1);
  }
}

__device__ __forceinline__ int lower_bound_s(const float* a, int n, float t) {
  int lo = 0, hi = n;
  while (lo < hi) {
    const int mid = (lo + hi) >> 1;
    if (a[mid] < t) lo = mid + 1; else hi = mid;
  }
  return lo;
}

// ---------------- Kernel 0: u = W @ w, Wh/Wl bf16 split transposed ---------
__global__ __launch_bounds__(256) void k0_prep(const float* __restrict__ W,
                                               const float* __restrict__ wl,
                                               const float* __restrict__ wr,
                                               float* __restrict__ u_l,
                                               float* __restrict__ u_r,
                                               u16* __restrict__ whT,
                                               u16* __restrict__ wloT) {
  const int t = threadIdx.x;
  const int blk = blockIdx.x;
  if (blk < 64) {
    const int k = blk * 4 + (t >> 6);
    const int lane = t & 63;
    const float w0 = W[k * FO + lane], w1 = W[k * FO + 64 + lane];
    float a1 = w0 * wl[lane] + w1 * wl[64 + lane];
    float a2 = w0 * wr[lane] + w1 * wr[64 + lane];
#pragma unroll
    for (int off = 1; off < 64; off <<= 1) {
      a1 += __shfl_xor(a1, off, 64);
      a2 += __shfl_xor(a2, off, 64);
    }
    if (lane == 0) { u_l[k] = a1; u_r[k] = a2; }
  } else {
#pragma unroll
    for (int e = 0; e < 2; ++e) {
      const int idx = (blk - 64) * 512 + t + e * 256;  // 0..32767
      const int col = idx >> 8, k = idx & 255;
      const float v = W[k * FO + col];
      const u16 h = f2bf(v);
      whT[col * KIN + k]  = h;
      wloT[col * KIN + k] = f2bf(v - bf2f(h));
    }
  }
}

// ---------------- Kernel 1: fused x-load -> f1/f2 + split-bf16 MFMA feats --
// grid 256 x 256. BM=64, BN=128, BK=64, 4 waves 2x2; wave-tile 32x64.
__global__ __launch_bounds__(256) void k1_fused(const float* __restrict__ x,
                                                const u16* __restrict__ whT,
                                                const u16* __restrict__ wloT,
                                                const float* __restrict__ u_l,
                                                const float* __restrict__ u_r,
                                                const float* __restrict__ blp,
                                                const float* __restrict__ brp,
                                                float* __restrict__ feats,
                                                float* __restrict__ f1g,
                                                float* __restrict__ f2g) {
  __shared__ u16 axh[64][72];
  __shared__ u16 axl[64][72];
  __shared__ u16 bwh[128][72];
  __shared__ u16 bwl[128][72];
  const int t = threadIdx.x;
  const int w = t >> 6, lane = t & 63;
  const int wm = w >> 1, wn = w & 1;
  const int row0 = blockIdx.x * 64;
  const int xr = t >> 3, xc = t & 7;   // staging: rows xr & xr+32, k-chunk xc
  f32x4 acc[2][4];
#pragma unroll
  for (int m = 0; m < 2; ++m)
#pragma unroll
    for (int n = 0; n < 4; ++n) acc[m][n] = (f32x4)0.f;

  float d1a = 0.f, d2a = 0.f, d1b = 0.f, d2b = 0.f;  // f1/f2 partials
  float4 xa0, xa1, xb0, xb1;
  bf16x8 wh_[4], wl_[4];

  // prologue prefetch (it = 0)
  {
    const float* pa = x + (size_t)(row0 + xr) * KIN + xc * 8;
    const float* pb = x + (size_t)(row0 + xr + 32) * KIN + xc * 8;
    xa0 = *(const float4*)pa; xa1 = *(const float4*)(pa + 4);
    xb0 = *(const float4*)pb; xb1 = *(const float4*)(pb + 4);
#pragma unroll
    for (int i = 0; i < 4; ++i) {
      const int v = t + i * 256;
      const int col = v >> 3, c = v & 7;
      wh_[i] = *(const bf16x8*)(whT + (size_t)col * KIN + c * 8);
      wl_[i] = *(const bf16x8*)(wloT + (size_t)col * KIN + c * 8);
    }
  }

  for (int it = 0; it < 4; ++it) {
    if (it) __syncthreads();   // previous compute done before overwrite
    {
      const float4 ul0 = *(const float4*)(u_l + it * 64 + xc * 8);
      const float4 ul1 = *(const float4*)(u_l + it * 64 + xc * 8 + 4);
      const float4 ur0 = *(const float4*)(u_r + it * 64 + xc * 8);
      const float4 ur1 = *(const float4*)(u_r + it * 64 + xc * 8 + 4);
      d1a += dot4(xa0, ul0) + dot4(xa1, ul1);
      d2a += dot4(xa0, ur0) + dot4(xa1, ur1);
      d1b += dot4(xb0, ul0) + dot4(xb1, ul1);
      d2b += dot4(xb0, ur0) + dot4(xb1, ur1);
    }
    {
      float va[8] = {xa0.x, xa0.y, xa0.z, xa0.w, xa1.x, xa1.y, xa1.z, xa1.w};
      float vb[8] = {xb0.x, xb0.y, xb0.z, xb0.w, xb1.x, xb1.y, xb1.z, xb1.w};
      bf16x8 ha, la, hb, lb;
#pragma unroll
      for (int q = 0; q < 8; ++q) {
        const u16 h1 = f2bf(va[q]);
        ha[q] = (short)h1; la[q] = (short)f2bf(va[q] - bf2f(h1));
        const u16 h2 = f2bf(vb[q]);
        hb[q] = (short)h2; lb[q] = (short)f2bf(vb[q] - bf2f(h2));
      }
      *(bf16x8*)(&axh[xr][xc * 8]) = ha;
      *(bf16x8*)(&axl[xr][xc * 8]) = la;
      *(bf16x8*)(&axh[xr + 32][xc * 8]) = hb;
      *(bf16x8*)(&axl[xr + 32][xc * 8]) = lb;
    }
#pragma unroll
    for (int i = 0; i < 4; ++i) {
      const int v = t + i * 256;
      const int col = v >> 3, c = v & 7;
      *(bf16x8*)(&bwh[col][c * 8]) = wh_[i];
      *(bf16x8*)(&bwl[col][c * 8]) = wl_[i];
    }
    __syncthreads();
    if (it < 3) {
      const float* pa = x + (size_t)(row0 + xr) * KIN + (it + 1) * 64 + xc * 8;
      const float* pb = x + (size_t)(row0 + xr + 32) * KIN + (it + 1) * 64 + xc * 8;
      xa0 = *(const float4*)pa; xa1 = *(const float4*)(pa + 4);
      xb0 = *(const float4*)pb; xb1 = *(const float4*)(pb + 4);
#pragma unroll
      for (int i = 0; i < 4; ++i) {
        const int v = t + i * 256;
        const int col = v >> 3, c = v & 7;
        wh_[i] = *(const bf16x8*)(whT + (size_t)col * KIN + (it + 1) * 64 + c * 8);
        wl_[i] = *(const bf16x8*)(wloT + (size_t)col * KIN + (it + 1) * 64 + c * 8);
      }
    }
#pragma unroll
    for (int kk = 0; kk < 2; ++kk) {
      const int kb = kk * 32 + (lane >> 4) * 8;
      bf16x8 ah[2], al[2], bh[4], blo[4];
#pragma unroll
      for (int m = 0; m < 2; ++m) {
        const int r = wm * 32 + m * 16 + (lane & 15);
        ah[m] = *(const bf16x8*)(&axh[r][kb]);
        al[m] = *(const bf16x8*)(&axl[r][kb]);
      }
#pragma unroll
      for (int n = 0; n < 4; ++n) {
        const int cidx = wn * 64 + n * 16 + (lane & 15);
        bh[n]  = *(const bf16x8*)(&bwh[cidx][kb]);
        blo[n] = *(const bf16x8*)(&bwl[cidx][kb]);
      }
#pragma unroll
      for (int m = 0; m < 2; ++m)
#pragma unroll
        for (int n = 0; n < 4; ++n) {
          acc[m][n] = __builtin_amdgcn_mfma_f32_16x16x32_bf16(ah[m], bh[n],  acc[m][n], 0, 0, 0);
          acc[m][n] = __builtin_amdgcn_mfma_f32_16x16x32_bf16(ah[m], blo[n], acc[m][n], 0, 0, 0);
          acc[m][n] = __builtin_amdgcn_mfma_f32_16x16x32_bf16(al[m], bh[n],  acc[m][n], 0, 0, 0);
        }
    }
  }

  // feats epilogue: C frag map col=lane&15, row=(lane>>4)*4+r
#pragma unroll
  for (int m = 0; m < 2; ++m) {
    const int rb = row0 + wm * 32 + m * 16 + (lane >> 4) * 4;
    const int cb = wn * 64 + (lane & 15);
#pragma unroll
    for (int n = 0; n < 4; ++n)
#pragma unroll
      for (int r = 0; r < 4; ++r)
        feats[(size_t)(rb + r) * FO + cb + n * 16] = acc[m][n][r];
  }

  // f1/f2 epilogue: reduce 8-lane groups (threads sharing row xr)
#pragma unroll
  for (int off = 1; off < 8; off <<= 1) {
    d1a += __shfl_xor(d1a, off, 64);
    d2a += __shfl_xor(d2a, off, 64);
    d1b += __shfl_xor(d1b, off, 64);
    d2b += __shfl_xor(d2b, off, 64);
  }
  if ((t & 7) == 0) {
    const float bl = blp[0], br = brp[0];
    f1g[row0 + xr] = d1a + bl;
    f2g[row0 + xr] = d2a + br;
    f1g[row0 + xr + 32] = d1b + bl;
    f2g[row0 + xr + 32] = d2b + br;
  }
}

// ---------------- Kernel 3a: hierarchical bitonic sorts + scans -------------
__global__ __launch_bounds__(1024, 1) void k3a_sort(const float* __restrict__ f1g,
                                                    const float* __restrict__ f2g,
                                                    float* __restrict__ f1sort,
                                                    float* __restrict__ sc1,
                                                    float* __restrict__ sc2,
                                                    float* __restrict__ f2sort,
                                                    int* __restrict__ jidxS) {
  __shared__ u64 lds[NN];          // 32 KiB
  __shared__ float wsumA[16], wsumB[16];
  const int t = threadIdx.x;
  const int lane = t & 63, wv = t >> 6;
  const int b = blockIdx.x & 3;
  const int task = blockIdx.x >> 2;
  const int base = b * NN;
  const float* __restrict__ src = task ? f2g : f1g;

  u64 e[4];
#pragma unroll
  for (int r = 0; r < 4; ++r) {
    const int i = 4 * t + r;
    e[r] = ((u64)f2key(src[base + i]) << 32) | (u32)i;
  }

  for (int k = 2; k <= 256; k <<= 1) reg_session(e, t, k);
#pragma unroll
  for (int r = 0; r < 4; ++r) lds[4 * t + r] = e[r];
  __syncthreads();

  for (int k = 512; k <= NN; k <<= 1) {
    for (int j = k >> 1; j >= 256; j >>= 1) {
#pragma unroll
      for (int pp = 0; pp < 2; ++pp) {
        const int p = t + pp * 1024;
        const int i = ((p & ~(j - 1)) << 1) | (p & (j - 1));
        const int ix = i | j;
        const bool up = ((i & k) == 0);
        const u64 a = lds[i], c = lds[ix];
        if ((a > c) == up) { lds[i] = c; lds[ix] = a; }
      }
      __syncthreads();
    }
#pragma unroll
    for (int r = 0; r < 4; ++r) e[r] = lds[4 * t + r];
    reg_session(e, t, k);
    if (k < NN) {
#pragma unroll
      for (int r = 0; r < 4; ++r) lds[4 * t + r] = e[r];
      __syncthreads();
    }
  }

  if (task == 0) {
    float kf[4], a[4], c[4];
#pragma unroll
    for (int r = 0; r < 4; ++r) {
      kf[r] = key2f((u32)(e[r] >> 32));
      f1sort[base + 4 * t + r] = kf[r];
      a[r] = expf(kf[r]);
      c[r] = expf(SLOPE * kf[r]);
    }
#pragma unroll
    for (int r = 1; r < 4; ++r) { a[r] += a[r - 1]; c[r] += c[r - 1]; }
    const float sa = a[3], sb = c[3];
    float pa = sa, pb = sb;
    for (int off = 1; off < 64; off <<= 1) {
      const float oa = __shfl_up(pa, off, 64);
      const float ob = __shfl_up(pb, off, 64);
      if (lane >= off) { pa += oa; pb += ob; }
    }
    if (lane == 63) { wsumA[wv] = pa; wsumB[wv] = pb; }
    __syncthreads();
    float wpa = 0.f, wpb = 0.f;
    for (int w2 = 0; w2 < wv; ++w2) { wpa += wsumA[w2]; wpb += wsumB[w2]; }
    const float basea = wpa + pa - sa, baseb = wpb + pb - sb;
#pragma unroll
    for (int r = 0; r < 4; ++r) {
      sc1[base + 4 * t + r] = basea + a[r];
      sc2[base + 4 * t + r] = baseb + c[r];
    }
  } else {
#pragma unroll
    for (int r = 0; r < 4; ++r) {
      f2sort[base + 4 * t + r] = key2f((u32)(e[r] >> 32));
      jidxS[base + 4 * t + r]  = (int)(e[r] & 0xffffffffu);
    }
  }
}

// ---------------- Kernel 4: LDS-staged alpha/beta + kpos + stride-4 prefixes
// grid NB*NCC x 128. Block (b,cc): stage f1sort/f2sort in LDS; 32 alpha/beta
// searches + 32 kpos searches (both in LDS); gather walk over 32 positions
// writing the inclusive prefix every 4th position.
__global__ __launch_bounds__(128) void k4_pref(const float* __restrict__ feats,
                                               const float* __restrict__ f1sort,
                                               const float* __restrict__ sc1,
                                               const float* __restrict__ sc2,
                                               const float* __restrict__ f2sort,
                                               const float* __restrict__ f1g,
                                               const int* __restrict__ jidxS,
                                               float* __restrict__ alphaS,
                                               float* __restrict__ betaS,
                                               int* __restrict__ kposA,
                                               float* __restrict__ finePreA,
                                               float* __restrict__ finePreB) {
  __shared__ float s_f1[NN];  // 16 KiB
  __shared__ float s_f2[NN];  // 16 KiB
  __shared__ float sal[CH], sbe[CH];
  const int b = blockIdx.x >> 7, cc = blockIdx.x & 127;
  const int tid = threadIdx.x;
  const int bb = b * NN;

  {  // stage sorted arrays (float4-coalesced, L2-hot)
    const float4* s1 = (const float4*)(f1sort + bb);
    const float4* s2 = (const float4*)(f2sort + bb);
    float4* t1 = (float4*)s_f1;
    float4* t2 = (float4*)s_f2;
#pragma unroll
    for (int i = 0; i < NN / 4 / 128; ++i) {
      t1[tid + i * 128] = s1[tid + i * 128];
      t2[tid + i * 128] = s2[tid + i * 128];
    }
  }
  __syncthreads();

  if (tid < CH) {
    // alpha/beta for sorted-j position pos = cc*CH + tid
    const int pos = cc * CH + tid;
    const float T1 = sc1[bb + NN - 1];
    const float f1max = s_f1[NN - 1];
    const float f2v = s_f2[pos];
    const float m = f1max + f2v;
    const float M = (m >= 0.f) ? m : SLOPE * m;      // column max of leaky scores
    const int pp = lower_bound_s(s_f1, NN, -f2v);    // first i with f1 >= -f2
    const float S1 = T1 - (pp > 0 ? sc1[bb + pp - 1] : 0.f);
    const float S2 = (pp > 0 ? sc2[bb + pp - 1] : 0.f);
    const float ea = expf(f2v - M);
    const float eb = expf(SLOPE * f2v - M);
    const float invD = 1.0f / (ea * S1 + eb * S2);
    const float al = ea * invD, be = eb * invD;
    sal[tid] = al; sbe[tid] = be;
    alphaS[bb + pos] = al; betaS[bb + pos] = be;     // for k5 residuals
  } else if (tid < 2 * CH) {
    // kpos for row cc*CH + (tid-CH)
    const int row = cc * CH + (tid - CH);
    const float f1v = f1g[bb + row];
    kposA[bb + row] = lower_bound_s(s_f2, NN, -f1v); // first sorted-j with f2 >= -f1
  }
  __syncthreads();

  // gather walk: inclusive prefix, stored every 4th position
  const int o = tid;
  const int base = bb + cc * CH;
  const int gbase = b * NGB + cc * (CH / 4);
  const float* fb = feats + (size_t)b * NN * FO;
  float accA = 0.f, accB = 0.f;
#pragma unroll 8
  for (int q = 0; q < CH; ++q) {
    const int kk = base + q;
    const int j = jidxS[kk];
    const float fv = fb[(size_t)j * FO + o];
    accA = fmaf(sal[q], fv, accA);
    accB = fmaf(sbe[q], fv, accB);
    if ((q & 3) == 3) {
      finePreA[(size_t)(gbase + (q >> 2)) * FO + o] = accA;
      finePreB[(size_t)(gbase + (q >> 2)) * FO + o] = accB;
    }
  }
}

// ---------------- Kernel 4c: exclusive prefix over chunk sums ---------------
__global__ __launch_bounds__(128) void k4c_coar(const float* __restrict__ finePreA,
                                                const float* __restrict__ finePreB,
                                                float* __restrict__ coarA,
                                                float* __restrict__ coarB) {
  const int b = blockIdx.x;
  const int o = threadIdx.x;
  float runA = 0.f, runB = 0.f;
#pragma unroll 8
  for (int c = 0; c < NCC; ++c) {
    coarA[(size_t)(b * (NCC + 1) + c) * FO + o] = runA;
    coarB[(size_t)(b * (NCC + 1) + c) * FO + o] = runB;
    runA += finePreA[(size_t)(b * NGB + c * (CH / 4) + (CH / 4) - 1) * FO + o];
    runB += finePreB[(size_t)(b * NGB + c * (CH / 4) + (CH / 4) - 1) * FO + o];
  }
  coarA[(size_t)(b * (NCC + 1) + NCC) * FO + o] = runA;   // total
  coarB[(size_t)(b * (NCC + 1) + NCC) * FO + o] = runB;
}

// ---------------- Kernel 5: streaming combine + <=3 residual gathers --------
__global__ __launch_bounds__(256) void k5_out(const float* __restrict__ feats,
                                              const float* __restrict__ alphaS,
                                              const float* __restrict__ betaS,
                                              const int* __restrict__ jidxS,
                                              const float* __restrict__ finePreA,
                                              const float* __restrict__ finePreB,
                                              const float* __restrict__ coarA,
                                              const float* __restrict__ coarB,
                                              const int* __restrict__ kposA,
                                              const float* __restrict__ f1g,
                                              float* __restrict__ out) {
  const int t = threadIdx.x;
  const int row = blockIdx.x * 2 + (t >> 7);
  const int o = t & 127;
  const int b = row >> 12;  // NN = 4096
  const int bb = b * NN;
  const int kp = kposA[row];
  const float f1v = f1g[row];
  const float e1 = expf(f1v), e2 = expf(SLOPE * f1v);
  const int c = kp >> 5;                 // chunk of 32 (c == NCC when kp == NN)

  float runA = coarA[(size_t)(b * (NCC + 1) + c) * FO + o];
  float runB = coarB[(size_t)(b * (NCC + 1) + c) * FO + o];
  const float totA = coarA[(size_t)(b * (NCC + 1) + NCC) * FO + o];
  const int gin = (kp >> 2) - c * (CH / 4);   // full groups within chunk
  if (gin > 0) {
    runA += finePreA[(size_t)(b * NGB + c * (CH / 4) + gin - 1) * FO + o];
    runB += finePreB[(size_t)(b * NGB + c * (CH / 4) + gin - 1) * FO + o];
  }
  const int res = kp & 3;                // row-uniform: no divergence
  const float* fb = feats + (size_t)b * NN * FO;
  for (int r = 0; r < res; ++r) {
    const int q = bb + kp - res + r;
    const int j = jidxS[q];
    const float fv = fb[(size_t)j * FO + o];
    runA = fmaf(alphaS[q], fv, runA);
    runB = fmaf(betaS[q], fv, runB);
  }
  out[(size_t)row * FO + o] = fmaf(e1, totA - runA, e2 * runB);
}

extern "C" void kernel_launch(void* const* d_in, const int* in_sizes, int n_in,
                              void* d_out, int out_size, void* d_ws, size_t ws_size,
                              hipStream_t stream) {
  const float* x  = (const float*)d_in[0];
  const float* W  = (const float*)d_in[1];
  const float* wl = (const float*)d_in[2];
  const float* bl = (const float*)d_in[3];
  const float* wr = (const float*)d_in[4];
  const float* br = (const float*)d_in[5];
  float* out = (float*)d_out;

  float* ws = (float*)d_ws;
  float* feats    = ws; ws += NROW * FO;
  float* finePreA = ws; ws += (NROW / 4) * FO;
  float* finePreB = ws; ws += (NROW / 4) * FO;
  float* f1g      = ws; ws += NROW;
  float* f2g      = ws; ws += NROW;
  float* f1sort   = ws; ws += NROW;
  float* f2sort   = ws; ws += NROW;
  float* sc1      = ws; ws += NROW;
  float* sc2      = ws; ws += NROW;
  float* alphaS   = ws; ws += NROW;
  float* betaS    = ws; ws += NROW;
  int* jidxS      = (int*)ws; ws += NROW;
  int* kposA      = (int*)ws; ws += NROW;
  float* coarA    = ws; ws += NB * (NCC + 1) * FO;
  float* coarB    = ws; ws += NB * (NCC + 1) * FO;
  float* u_l      = ws; ws += KIN;
  float* u_r      = ws; ws += KIN;
  u16* whT  = (u16*)ws; ws += FO * KIN / 2;     // bf16 [128 col][256 k]
  u16* wloT = (u16*)ws; ws += FO * KIN / 2;
  (void)in_sizes; (void)n_in; (void)out_size; (void)ws_size;

  hipLaunchKernelGGL(k0_prep,  dim3(128),       dim3(256),  0, stream,
                     W, wl, wr, u_l, u_r, whT, wloT);
  hipLaunchKernelGGL(k1_fused, dim3(NROW / 64), dim3(256),  0, stream,
                     x, whT, wloT, u_l, u_r, bl, br, feats, f1g, f2g);
  hipLaunchKernelGGL(k3a_sort, dim3(8),         dim3(1024), 0, stream,
                     f1g, f2g, f1sort, sc1, sc2, f2sort, jidxS);
  hipLaunchKernelGGL(k4_pref,  dim3(NB * NCC),  dim3(128),  0, stream,
                     feats, f1sort, sc1, sc2, f2sort, f1g, jidxS,
                     alphaS, betaS, kposA, finePreA, finePreB);
  hipLaunchKernelGGL(k4c_coar, dim3(NB),        dim3(128),  0, stream,
                     finePreA, finePreB, coarA, coarB);
  hipLaunchKernelGGL(k5_out,   dim3(NROW / 2),  dim3(256),  0, stream,
                     feats, alphaS, betaS, jidxS, finePreA, finePreB,
                     coarA, coarB, kposA, f1g, out);
}

// Round 13
// 70.768 us; speedup vs baseline: 1.0771x; 1.0771x over previous
//
#include <hip/hip_runtime.h>

using u16 = unsigned short;
using u32 = unsigned int;
using u64 = unsigned long long;

typedef short bf16x8 __attribute__((ext_vector_type(8)));
typedef float f32x4 __attribute__((ext_vector_type(4)));

static constexpr int NB  = 4;     // batch
static constexpr int NN  = 4096;  // nodes
static constexpr int KIN = 256;   // in features
static constexpr int FO  = 128;   // out features
static constexpr int NROW = NB * NN;  // 16384 total rows
static constexpr int NCC = 64;    // coarse chunks per batch (64 positions each)
static constexpr float SLOPE = 0.01f;

// ---- bf16 helpers (RNE, no NaN inputs) ----
__device__ __forceinline__ u16 f2bf(float f) {
  const u32 u = __float_as_uint(f);
  return (u16)((u + 0x7fffu + ((u >> 16) & 1u)) >> 16);
}
__device__ __forceinline__ float bf2f(u16 h) {
  return __uint_as_float(((u32)h) << 16);
}
__device__ __forceinline__ float dot4(const float4& a, const float4& b) {
  return a.x * b.x + a.y * b.y + a.z * b.z + a.w * b.w;
}

// monotone bijection f32 -> orderable u32 (no NaNs present)
__device__ __forceinline__ u32 f2key(float f) {
  const u32 b = __float_as_uint(f);
  return (b & 0x80000000u) ? ~b : (b | 0x80000000u);
}
__device__ __forceinline__ float key2f(u32 u) {
  const u32 b = (u & 0x80000000u) ? (u ^ 0x80000000u) : ~u;
  return __uint_as_float(b);
}

__device__ __forceinline__ u64 shfl_xor64(u64 v, int m) {
  const u32 lo = __shfl_xor((u32)(v & 0xffffffffu), m, 64);
  const u32 hi = __shfl_xor((u32)(v >> 32), m, 64);
  return ((u64)hi << 32) | (u64)lo;
}
__device__ __forceinline__ void cswap(u64& a, u64& b, bool up) {
  if ((a > b) == up) { const u64 tmp = a; a = b; b = tmp; }
}

// bitonic rounds j = min(k/2,128)..1 for phase k, data in registers.
__device__ __forceinline__ void reg_session(u64 e[4], int t, int k) {
  const int jstart = (k > 256) ? 128 : (k >> 1);
  for (int j = jstart; j >= 4; j >>= 1) {
    const int J = j >> 2;
    const bool up   = ((t & (k >> 2)) == 0);
    const bool lowr = ((t & J) == 0);
#pragma unroll
    for (int r = 0; r < 4; ++r) {
      const u64 o = shfl_xor64(e[r], J);
      const bool less = e[r] < o;              // keys unique (idx tie-break)
      e[r] = ((lowr == up) == less) ? e[r] : o;
    }
  }
  if (k >= 4) {
    const bool up = ((t & (k >> 2)) == 0);
    cswap(e[0], e[2], up); cswap(e[1], e[3], up);
  }
  {
    const bool up0 = (((4 * t)     & k) == 0);
    const bool up1 = (((4 * t + 2) & k) == 0);
    cswap(e[0], e[1], up0); cswap(e[2], e[3], up1);
  }
}

__device__ __forceinline__ int lower_bound_s(const float* a, int n, float t) {
  int lo = 0, hi = n;
  while (lo < hi) {
    const int mid = (lo + hi) >> 1;
    if (a[mid] < t) lo = mid + 1; else hi = mid;
  }
  return lo;
}

// ---------------- Kernel 0: W split + exact f1/f2 (pre-GEMM) ---------------
// grid 256 x 256. Every block: u_l/u_r in LDS (thread t = k-row), then
// f1/f2 for 64 rows (wave per 16 rows, lane-parallel dot + shfl reduce).
// Blocks 0-63 additionally write the Wh/Wl bf16 transposed split.
__global__ __launch_bounds__(256) void k0_prep(const float* __restrict__ x,
                                               const float* __restrict__ W,
                                               const float* __restrict__ wl,
                                               const float* __restrict__ blp,
                                               const float* __restrict__ wr,
                                               const float* __restrict__ brp,
                                               u16* __restrict__ whT,
                                               u16* __restrict__ wloT,
                                               float* __restrict__ f1g,
                                               float* __restrict__ f2g) {
  __shared__ float uls[KIN];
  __shared__ float urs[KIN];
  const int t = threadIdx.x;
  const int bid = blockIdx.x;

  if (bid < 64) {  // W hi/lo split transpose
#pragma unroll
    for (int e = 0; e < 2; ++e) {
      const int idx = bid * 512 + t + e * 256;  // 0..32767
      const int col = idx >> 8, k = idx & 255;
      const float v = W[k * FO + col];
      const u16 h = f2bf(v);
      whT[col * KIN + k]  = h;
      wloT[col * KIN + k] = f2bf(v - bf2f(h));
    }
  }
  // u_l[k]/u_r[k] for k = t (exact f32 serial dot; W L2-hot)
  {
    const float* Wr = W + (size_t)t * FO;
    float s1 = 0.f, s2 = 0.f;
#pragma unroll 8
    for (int c = 0; c < FO; ++c) {
      const float wv = Wr[c];
      s1 = fmaf(wv, wl[c], s1);
      s2 = fmaf(wv, wr[c], s2);
    }
    uls[t] = s1; urs[t] = s2;
  }
  __syncthreads();
  // f1/f2: wave wv handles 16 rows serially; 64 lanes x float4 covers a row
  const int wv = t >> 6, lane = t & 63;
  const int row0 = bid * 64 + wv * 16;
  const float4 ul = *(const float4*)(&uls[lane * 4]);
  const float4 ur = *(const float4*)(&urs[lane * 4]);
  const float blv = blp[0], brv = brp[0];
  for (int r = 0; r < 16; ++r) {
    const int row = row0 + r;
    const float4 xv = *(const float4*)(x + (size_t)row * KIN + lane * 4);
    float d1 = dot4(xv, ul);
    float d2 = dot4(xv, ur);
#pragma unroll
    for (int off = 1; off < 64; off <<= 1) {
      d1 += __shfl_xor(d1, off, 64);
      d2 += __shfl_xor(d2, off, 64);
    }
    if (lane == 0) { f1g[row] = d1 + blv; f2g[row] = d2 + brv; }
  }
}

// ---------------- Kernel B: sort (blocks 0-7) || MFMA GEMM (blocks 8-263) --
// Sort path: R8 k3a verbatim. GEMM path: R9 phase-1 tiling (verified):
// BM=64, 16 waves 4x4, wave-tile 16x32, BK=64 x 4, split-bf16 3-term MFMA.
__global__ __launch_bounds__(1024, 1) void kB_main(const float* __restrict__ x,
                                                   const u16* __restrict__ whT,
                                                   const u16* __restrict__ wloT,
                                                   const float* __restrict__ f1g,
                                                   const float* __restrict__ f2g,
                                                   float* __restrict__ feats,
                                                   float* __restrict__ f1sort,
                                                   float* __restrict__ sc1,
                                                   float* __restrict__ sc2,
                                                   float* __restrict__ f2sort,
                                                   int* __restrict__ jidxS) {
  __shared__ __align__(16) unsigned char smem[55296];
  const int tid = threadIdx.x;
  const int bid = blockIdx.x;

  if (bid < 8) {
    // ======== hierarchical bitonic sort + exp scans (R8 k3a) ========
    u64* lds = (u64*)smem;                  // [4096] = 32 KiB
    float* wsumA = (float*)(smem + 32768);  // [16]
    float* wsumB = (float*)(smem + 32832);  // [16]
    const int t = tid;
    const int lane = t & 63, wv = t >> 6;
    const int b = bid & 3;
    const int task = bid >> 2;
    const int base = b * NN;
    const float* __restrict__ src = task ? f2g : f1g;

    u64 e[4];
#pragma unroll
    for (int r = 0; r < 4; ++r) {
      const int i = 4 * t + r;
      e[r] = ((u64)f2key(src[base + i]) << 32) | (u32)i;
    }
    for (int k = 2; k <= 256; k <<= 1) reg_session(e, t, k);
#pragma unroll
    for (int r = 0; r < 4; ++r) lds[4 * t + r] = e[r];
    __syncthreads();
    for (int k = 512; k <= NN; k <<= 1) {
      for (int j = k >> 1; j >= 256; j >>= 1) {
#pragma unroll
        for (int pp = 0; pp < 2; ++pp) {
          const int pw = t + pp * 1024;
          const int i = ((pw & ~(j - 1)) << 1) | (pw & (j - 1));
          const int ix = i | j;
          const bool up = ((i & k) == 0);
          const u64 a = lds[i], c = lds[ix];
          if ((a > c) == up) { lds[i] = c; lds[ix] = a; }
        }
        __syncthreads();
      }
#pragma unroll
      for (int r = 0; r < 4; ++r) e[r] = lds[4 * t + r];
      reg_session(e, t, k);
      if (k < NN) {
#pragma unroll
        for (int r = 0; r < 4; ++r) lds[4 * t + r] = e[r];
        __syncthreads();
      }
    }
    if (task == 0) {
      float kf[4], a[4], c[4];
#pragma unroll
      for (int r = 0; r < 4; ++r) {
        kf[r] = key2f((u32)(e[r] >> 32));
        f1sort[base + 4 * t + r] = kf[r];
        a[r] = expf(kf[r]);
        c[r] = expf(SLOPE * kf[r]);
      }
#pragma unroll
      for (int r = 1; r < 4; ++r) { a[r] += a[r - 1]; c[r] += c[r - 1]; }
      const float sa = a[3], sb = c[3];
      float pa = sa, pb = sb;
      for (int off = 1; off < 64; off <<= 1) {
        const float oa = __shfl_up(pa, off, 64);
        const float ob = __shfl_up(pb, off, 64);
        if (lane >= off) { pa += oa; pb += ob; }
      }
      if (lane == 63) { wsumA[wv] = pa; wsumB[wv] = pb; }
      __syncthreads();
      float wpa = 0.f, wpb = 0.f;
      for (int w2 = 0; w2 < wv; ++w2) { wpa += wsumA[w2]; wpb += wsumB[w2]; }
      const float basea = wpa + pa - sa, baseb = wpb + pb - sb;
#pragma unroll
      for (int r = 0; r < 4; ++r) {
        sc1[base + 4 * t + r] = basea + a[r];
        sc2[base + 4 * t + r] = baseb + c[r];
      }
    } else {
#pragma unroll
      for (int r = 0; r < 4; ++r) {
        f2sort[base + 4 * t + r] = key2f((u32)(e[r] >> 32));
        jidxS[base + 4 * t + r]  = (int)(e[r] & 0xffffffffu);
      }
    }
  } else {
    // ======== split-bf16 MFMA GEMM (R9 phase-1 tiling) ========
    u16* axh = (u16*)smem;                 // [64][72]
    u16* axl = (u16*)(smem + 9216);
    u16* bwh = (u16*)(smem + 18432);       // [128][72]
    u16* bwl = (u16*)(smem + 36864);
    const int w = tid >> 6, lane = tid & 63;
    const int wm = w >> 2, wn = w & 3;
    const int row0 = (bid - 8) * 64;
    const int xr = tid >> 4, xc4 = (tid & 15) * 4;   // x staging: 64r x 16 f4
    const int wcol = tid >> 3, wc = tid & 7;         // W staging: 128c x 8 b8
    f32x4 acc[2];
    acc[0] = (f32x4)0.f; acc[1] = (f32x4)0.f;
    float4 xv;
    bf16x8 whb, wlb;
    xv  = *(const float4*)(x + (size_t)(row0 + xr) * KIN + xc4);
    whb = *(const bf16x8*)(whT  + (size_t)wcol * KIN + wc * 8);
    wlb = *(const bf16x8*)(wloT + (size_t)wcol * KIN + wc * 8);

    for (int it = 0; it < 4; ++it) {
      if (it) __syncthreads();
      {
        float va[4] = {xv.x, xv.y, xv.z, xv.w};
        ushort4 hh, ll;
        const u16 h0 = f2bf(va[0]); hh.x = h0; ll.x = f2bf(va[0] - bf2f(h0));
        const u16 h1 = f2bf(va[1]); hh.y = h1; ll.y = f2bf(va[1] - bf2f(h1));
        const u16 h2 = f2bf(va[2]); hh.z = h2; ll.z = f2bf(va[2] - bf2f(h2));
        const u16 h3 = f2bf(va[3]); hh.w = h3; ll.w = f2bf(va[3] - bf2f(h3));
        *(ushort4*)(&axh[xr * 72 + xc4]) = hh;
        *(ushort4*)(&axl[xr * 72 + xc4]) = ll;
      }
      *(bf16x8*)(&bwh[wcol * 72 + wc * 8]) = whb;
      *(bf16x8*)(&bwl[wcol * 72 + wc * 8]) = wlb;
      __syncthreads();
      if (it < 3) {  // prefetch next k-chunk (overlaps MFMA)
        xv  = *(const float4*)(x + (size_t)(row0 + xr) * KIN + (it + 1) * 64 + xc4);
        whb = *(const bf16x8*)(whT  + (size_t)wcol * KIN + (it + 1) * 64 + wc * 8);
        wlb = *(const bf16x8*)(wloT + (size_t)wcol * KIN + (it + 1) * 64 + wc * 8);
      }
#pragma unroll
      for (int kk = 0; kk < 2; ++kk) {
        const int kb = kk * 32 + (lane >> 4) * 8;
        const int ar = wm * 16 + (lane & 15);
        const bf16x8 ah = *(const bf16x8*)(&axh[ar * 72 + kb]);
        const bf16x8 al = *(const bf16x8*)(&axl[ar * 72 + kb]);
#pragma unroll
        for (int n = 0; n < 2; ++n) {
          const int cidx = wn * 32 + n * 16 + (lane & 15);
          const bf16x8 bh  = *(const bf16x8*)(&bwh[cidx * 72 + kb]);
          const bf16x8 blo = *(const bf16x8*)(&bwl[cidx * 72 + kb]);
          acc[n] = __builtin_amdgcn_mfma_f32_16x16x32_bf16(ah, bh,  acc[n], 0, 0, 0);
          acc[n] = __builtin_amdgcn_mfma_f32_16x16x32_bf16(ah, blo, acc[n], 0, 0, 0);
          acc[n] = __builtin_amdgcn_mfma_f32_16x16x32_bf16(al, bh,  acc[n], 0, 0, 0);
        }
      }
    }
    // epilogue: C map col=lane&15, row=(lane>>4)*4+r
    const int rb = row0 + wm * 16 + (lane >> 4) * 4;
    const int cb = wn * 32 + (lane & 15);
#pragma unroll
    for (int n = 0; n < 2; ++n)
#pragma unroll
      for (int r = 0; r < 4; ++r)
        feats[(size_t)(rb + r) * FO + cb + n * 16] = acc[n][r];
  }
}

// ---------------- Kernel 3b: alpha/beta per sorted-j, kpos/E1/E2 per row ----
__global__ __launch_bounds__(512) void k3b_ab(const float* __restrict__ f1sort,
                                              const float* __restrict__ sc1,
                                              const float* __restrict__ sc2,
                                              const float* __restrict__ f2sort,
                                              const float* __restrict__ f1g,
                                              float* __restrict__ alphaS,
                                              float* __restrict__ betaS,
                                              int* __restrict__ kposA,
                                              float* __restrict__ E1g,
                                              float* __restrict__ E2g) {
  __shared__ float s_f1[NN];  // 16 KiB
  __shared__ float s_f2[NN];  // 16 KiB
  const int b = blockIdx.x >> 3;
  const int part = blockIdx.x & 7;
  const int base = b * NN;
  for (int i = threadIdx.x; i < NN; i += 512) {
    s_f1[i] = f1sort[base + i];
    s_f2[i] = f2sort[base + i];
  }
  __syncthreads();
  const int g = part * 512 + threadIdx.x;
  const float T1 = sc1[base + NN - 1];
  const float f1max = s_f1[NN - 1];
  {
    const float f2v = s_f2[g];
    const float m = f1max + f2v;
    const float M = (m >= 0.f) ? m : SLOPE * m;      // column max of leaky scores
    const int p = lower_bound_s(s_f1, NN, -f2v);     // first i with f1 >= -f2
    const float S1 = T1 - (p > 0 ? sc1[base + p - 1] : 0.f);
    const float S2 = (p > 0 ? sc2[base + p - 1] : 0.f);
    const float ea = expf(f2v - M);
    const float eb = expf(SLOPE * f2v - M);
    const float invD = 1.0f / (ea * S1 + eb * S2);
    alphaS[base + g] = ea * invD;
    betaS[base + g]  = eb * invD;
  }
  {
    const float f1v = f1g[base + g];
    kposA[base + g] = lower_bound_s(s_f2, NN, -f1v); // first sorted-j with f2 >= -f1
    E1g[base + g] = expf(f1v);
    E2g[base + g] = expf(SLOPE * f1v);
  }
}

// ---------------- Kernel 4a: per-position inclusive prefixes ----------------
__global__ __launch_bounds__(128) void k4a_pref(const float* __restrict__ feats,
                                                const float* __restrict__ alphaS,
                                                const float* __restrict__ betaS,
                                                const int* __restrict__ jidxS,
                                                float* __restrict__ finePreA,
                                                float* __restrict__ finePreB) {
  const int b = blockIdx.x >> 6, cc = blockIdx.x & 63;
  const int o = threadIdx.x;
  const int base = b * NN + cc * 64;
  const float* fb = feats + (size_t)b * NN * FO;
  float accA = 0.f, accB = 0.f;
#pragma unroll 8
  for (int q = 0; q < 64; ++q) {
    const int kk = base + q;
    const int j = jidxS[kk];
    const float fv = fb[(size_t)j * FO + o];
    accA = fmaf(alphaS[kk], fv, accA);
    accB = fmaf(betaS[kk], fv, accB);
    finePreA[(size_t)kk * FO + o] = accA;
    finePreB[(size_t)kk * FO + o] = accB;
  }
}

// ---------------- Kernel 4c: exclusive prefix over coarse sums --------------
__global__ __launch_bounds__(128) void k4c_coar(const float* __restrict__ finePreA,
                                                const float* __restrict__ finePreB,
                                                float* __restrict__ coarA,
                                                float* __restrict__ coarB) {
  const int b = blockIdx.x;
  const int o = threadIdx.x;
  float runA = 0.f, runB = 0.f;
#pragma unroll
  for (int c = 0; c < NCC; ++c) {
    coarA[(size_t)(b * (NCC + 1) + c) * FO + o] = runA;
    coarB[(size_t)(b * (NCC + 1) + c) * FO + o] = runB;
    runA += finePreA[(size_t)(b * NN + c * 64 + 63) * FO + o];
    runB += finePreB[(size_t)(b * NN + c * 64 + 63) * FO + o];
  }
  coarA[(size_t)(b * (NCC + 1) + NCC) * FO + o] = runA;   // total
  coarB[(size_t)(b * (NCC + 1) + NCC) * FO + o] = runB;
}

// ---------------- Kernel 5: streaming combine (no gathers) ------------------
__global__ __launch_bounds__(256) void k5_out(const float* __restrict__ finePreA,
                                              const float* __restrict__ finePreB,
                                              const float* __restrict__ coarA,
                                              const float* __restrict__ coarB,
                                              const int* __restrict__ kposA,
                                              const float* __restrict__ E1g,
                                              const float* __restrict__ E2g,
                                              float* __restrict__ out) {
  const int t = threadIdx.x;
  const int row = blockIdx.x * 2 + (t >> 7);
  const int o = t & 127;
  const int b = row >> 12;  // NN = 4096
  const int kp = kposA[row];
  const float e1 = E1g[row], e2 = E2g[row];
  const int c = kp >> 6;          // 0..64

  float runA = coarA[(size_t)(b * (NCC + 1) + c) * FO + o];
  float runB = coarB[(size_t)(b * (NCC + 1) + c) * FO + o];
  const float totA = coarA[(size_t)(b * (NCC + 1) + NCC) * FO + o];
  if (kp & 63) {
    runA += finePreA[(size_t)(b * NN + kp - 1) * FO + o];
    runB += finePreB[(size_t)(b * NN + kp - 1) * FO + o];
  }
  out[(size_t)row * FO + o] = fmaf(e1, totA - runA, e2 * runB);
}

extern "C" void kernel_launch(void* const* d_in, const int* in_sizes, int n_in,
                              void* d_out, int out_size, void* d_ws, size_t ws_size,
                              hipStream_t stream) {
  const float* x  = (const float*)d_in[0];
  const float* W  = (const float*)d_in[1];
  const float* wl = (const float*)d_in[2];
  const float* bl = (const float*)d_in[3];
  const float* wr = (const float*)d_in[4];
  const float* br = (const float*)d_in[5];
  float* out = (float*)d_out;

  float* ws = (float*)d_ws;
  float* feats    = ws; ws += NROW * FO;
  float* finePreA = ws; ws += NROW * FO;
  float* finePreB = ws; ws += NROW * FO;
  float* f1g      = ws; ws += NROW;
  float* f2g      = ws; ws += NROW;
  float* f1sort   = ws; ws += NROW;
  float* f2sort   = ws; ws += NROW;
  float* sc1      = ws; ws += NROW;
  float* sc2      = ws; ws += NROW;
  float* alphaS   = ws; ws += NROW;
  float* betaS    = ws; ws += NROW;
  float* E1g      = ws; ws += NROW;
  float* E2g      = ws; ws += NROW;
  int* jidxS      = (int*)ws; ws += NROW;
  int* kposA      = (int*)ws; ws += NROW;
  float* coarA    = ws; ws += NB * (NCC + 1) * FO;
  float* coarB    = ws; ws += NB * (NCC + 1) * FO;
  u16* whT  = (u16*)ws; ws += FO * KIN / 2;     // bf16 [128 col][256 k]
  u16* wloT = (u16*)ws; ws += FO * KIN / 2;
  (void)in_sizes; (void)n_in; (void)out_size; (void)ws_size;

  hipLaunchKernelGGL(k0_prep,  dim3(NROW / 64),     dim3(256),  0, stream,
                     x, W, wl, bl, wr, br, whT, wloT, f1g, f2g);
  hipLaunchKernelGGL(kB_main,  dim3(8 + NROW / 64), dim3(1024), 0, stream,
                     x, whT, wloT, f1g, f2g, feats,
                     f1sort, sc1, sc2, f2sort, jidxS);
  hipLaunchKernelGGL(k3b_ab,   dim3(NB * 8),        dim3(512),  0, stream,
                     f1sort, sc1, sc2, f2sort, f1g, alphaS, betaS, kposA, E1g, E2g);
  hipLaunchKernelGGL(k4a_pref, dim3(NB * NCC),      dim3(128),  0, stream,
                     feats, alphaS, betaS, jidxS, finePreA, finePreB);
  hipLaunchKernelGGL(k4c_coar, dim3(NB),            dim3(128),  0, stream,
                     finePreA, finePreB, coarA, coarB);
  hipLaunchKernelGGL(k5_out,   dim3(NROW / 2),      dim3(256),  0, stream,
                     finePreA, finePreB, coarA, coarB, kposA, E1g, E2g, out);
}

// Round 14
// 70.114 us; speedup vs baseline: 1.0871x; 1.0093x over previous
//
#include <hip/hip_runtime.h>

using u16 = unsigned short;
using u32 = unsigned int;
using u64 = unsigned long long;

typedef short bf16x8 __attribute__((ext_vector_type(8)));
typedef float f32x4 __attribute__((ext_vector_type(4)));

static constexpr int NB  = 4;     // batch
static constexpr int NN  = 4096;  // nodes
static constexpr int KIN = 256;   // in features
static constexpr int FO  = 128;   // out features
static constexpr int NROW = NB * NN;  // 16384 total rows
static constexpr int NCC = 128;   // chunks per batch
static constexpr int CH  = 32;    // positions per chunk
static constexpr float SLOPE = 0.01f;

// ---- bf16 helpers (RNE, no NaN inputs) ----
__device__ __forceinline__ u16 f2bf(float f) {
  const u32 u = __float_as_uint(f);
  return (u16)((u + 0x7fffu + ((u >> 16) & 1u)) >> 16);
}
__device__ __forceinline__ float bf2f(u16 h) {
  return __uint_as_float(((u32)h) << 16);
}
__device__ __forceinline__ float dot4(const float4& a, const float4& b) {
  return a.x * b.x + a.y * b.y + a.z * b.z + a.w * b.w;
}

// monotone bijection f32 -> orderable u32 (no NaNs present)
__device__ __forceinline__ u32 f2key(float f) {
  const u32 b = __float_as_uint(f);
  return (b & 0x80000000u) ? ~b : (b | 0x80000000u);
}
__device__ __forceinline__ float key2f(u32 u) {
  const u32 b = (u & 0x80000000u) ? (u ^ 0x80000000u) : ~u;
  return __uint_as_float(b);
}

__device__ __forceinline__ u64 shfl_xor64(u64 v, int m) {
  const u32 lo = __shfl_xor((u32)(v & 0xffffffffu), m, 64);
  const u32 hi = __shfl_xor((u32)(v >> 32), m, 64);
  return ((u64)hi << 32) | (u64)lo;
}
__device__ __forceinline__ void cswap(u64& a, u64& b, bool up) {
  if ((a > b) == up) { const u64 tmp = a; a = b; b = tmp; }
}

// bitonic rounds j = min(k/2,128)..1 for phase k, data in registers.
__device__ __forceinline__ void reg_session(u64 e[4], int t, int k) {
  const int jstart = (k > 256) ? 128 : (k >> 1);
  for (int j = jstart; j >= 4; j >>= 1) {
    const int J = j >> 2;
    const bool up   = ((t & (k >> 2)) == 0);
    const bool lowr = ((t & J) == 0);
#pragma unroll
    for (int r = 0; r < 4; ++r) {
      const u64 o = shfl_xor64(e[r], J);
      const bool less = e[r] < o;              // keys unique (idx tie-break)
      e[r] = ((lowr == up) == less) ? e[r] : o;
    }
  }
  if (k >= 4) {
    const bool up = ((t & (k >> 2)) == 0);
    cswap(e[0], e[2], up); cswap(e[1], e[3], up);
  }
  {
    const bool up0 = (((4 * t)     & k) == 0);
    const bool up1 = (((4 * t + 2) & k) == 0);
    cswap(e[0], e[1], up0); cswap(e[2], e[3], up1);
  }
}

__device__ __forceinline__ int lower_bound_s(const float* a, int n, float t) {
  int lo = 0, hi = n;
  while (lo < hi) {
    const int mid = (lo + hi) >> 1;
    if (a[mid] < t) lo = mid + 1; else hi = mid;
  }
  return lo;
}

// ---------------- Kernel 0: u = W @ w, Wh/Wl bf16 split transposed ---------
__global__ __launch_bounds__(256) void k0_prep(const float* __restrict__ W,
                                               const float* __restrict__ wl,
                                               const float* __restrict__ wr,
                                               float* __restrict__ u_l,
                                               float* __restrict__ u_r,
                                               u16* __restrict__ whT,
                                               u16* __restrict__ wloT) {
  const int t = threadIdx.x;
  const int blk = blockIdx.x;
  if (blk < 64) {
    const int k = blk * 4 + (t >> 6);
    const int lane = t & 63;
    const float w0 = W[k * FO + lane], w1 = W[k * FO + 64 + lane];
    float a1 = w0 * wl[lane] + w1 * wl[64 + lane];
    float a2 = w0 * wr[lane] + w1 * wr[64 + lane];
#pragma unroll
    for (int off = 1; off < 64; off <<= 1) {
      a1 += __shfl_xor(a1, off, 64);
      a2 += __shfl_xor(a2, off, 64);
    }
    if (lane == 0) { u_l[k] = a1; u_r[k] = a2; }
  } else {
#pragma unroll
    for (int e = 0; e < 2; ++e) {
      const int idx = (blk - 64) * 512 + t + e * 256;  // 0..32767
      const int col = idx >> 8, k = idx & 255;
      const float v = W[k * FO + col];
      const u16 h = f2bf(v);
      whT[col * KIN + k]  = h;
      wloT[col * KIN + k] = f2bf(v - bf2f(h));
    }
  }
}

// ---------------- Kernel 1: fused x-load -> f1/f2 + split-bf16 MFMA feats --
// grid 256 x 256. BM=64, BN=128, BK=64, 4 waves 2x2; wave-tile 32x64.
__global__ __launch_bounds__(256) void k1_fused(const float* __restrict__ x,
                                                const u16* __restrict__ whT,
                                                const u16* __restrict__ wloT,
                                                const float* __restrict__ u_l,
                                                const float* __restrict__ u_r,
                                                const float* __restrict__ blp,
                                                const float* __restrict__ brp,
                                                float* __restrict__ feats,
                                                float* __restrict__ f1g,
                                                float* __restrict__ f2g) {
  __shared__ u16 axh[64][72];
  __shared__ u16 axl[64][72];
  __shared__ u16 bwh[128][72];
  __shared__ u16 bwl[128][72];
  const int t = threadIdx.x;
  const int w = t >> 6, lane = t & 63;
  const int wm = w >> 1, wn = w & 1;
  const int row0 = blockIdx.x * 64;
  const int xr = t >> 3, xc = t & 7;   // staging: rows xr & xr+32, k-chunk xc
  f32x4 acc[2][4];
#pragma unroll
  for (int m = 0; m < 2; ++m)
#pragma unroll
    for (int n = 0; n < 4; ++n) acc[m][n] = (f32x4)0.f;

  float d1a = 0.f, d2a = 0.f, d1b = 0.f, d2b = 0.f;  // f1/f2 partials
  float4 xa0, xa1, xb0, xb1;
  bf16x8 wh_[4], wl_[4];

  // prologue prefetch (it = 0)
  {
    const float* pa = x + (size_t)(row0 + xr) * KIN + xc * 8;
    const float* pb = x + (size_t)(row0 + xr + 32) * KIN + xc * 8;
    xa0 = *(const float4*)pa; xa1 = *(const float4*)(pa + 4);
    xb0 = *(const float4*)pb; xb1 = *(const float4*)(pb + 4);
#pragma unroll
    for (int i = 0; i < 4; ++i) {
      const int v = t + i * 256;
      const int col = v >> 3, c = v & 7;
      wh_[i] = *(const bf16x8*)(whT + (size_t)col * KIN + c * 8);
      wl_[i] = *(const bf16x8*)(wloT + (size_t)col * KIN + c * 8);
    }
  }

  for (int it = 0; it < 4; ++it) {
    if (it) __syncthreads();   // previous compute done before overwrite
    {
      const float4 ul0 = *(const float4*)(u_l + it * 64 + xc * 8);
      const float4 ul1 = *(const float4*)(u_l + it * 64 + xc * 8 + 4);
      const float4 ur0 = *(const float4*)(u_r + it * 64 + xc * 8);
      const float4 ur1 = *(const float4*)(u_r + it * 64 + xc * 8 + 4);
      d1a += dot4(xa0, ul0) + dot4(xa1, ul1);
      d2a += dot4(xa0, ur0) + dot4(xa1, ur1);
      d1b += dot4(xb0, ul0) + dot4(xb1, ul1);
      d2b += dot4(xb0, ur0) + dot4(xb1, ur1);
    }
    {
      float va[8] = {xa0.x, xa0.y, xa0.z, xa0.w, xa1.x, xa1.y, xa1.z, xa1.w};
      float vb[8] = {xb0.x, xb0.y, xb0.z, xb0.w, xb1.x, xb1.y, xb1.z, xb1.w};
      bf16x8 ha, la, hb, lb;
#pragma unroll
      for (int q = 0; q < 8; ++q) {
        const u16 h1 = f2bf(va[q]);
        ha[q] = (short)h1; la[q] = (short)f2bf(va[q] - bf2f(h1));
        const u16 h2 = f2bf(vb[q]);
        hb[q] = (short)h2; lb[q] = (short)f2bf(vb[q] - bf2f(h2));
      }
      *(bf16x8*)(&axh[xr][xc * 8]) = ha;
      *(bf16x8*)(&axl[xr][xc * 8]) = la;
      *(bf16x8*)(&axh[xr + 32][xc * 8]) = hb;
      *(bf16x8*)(&axl[xr + 32][xc * 8]) = lb;
    }
#pragma unroll
    for (int i = 0; i < 4; ++i) {
      const int v = t + i * 256;
      const int col = v >> 3, c = v & 7;
      *(bf16x8*)(&bwh[col][c * 8]) = wh_[i];
      *(bf16x8*)(&bwl[col][c * 8]) = wl_[i];
    }
    __syncthreads();
    if (it < 3) {
      const float* pa = x + (size_t)(row0 + xr) * KIN + (it + 1) * 64 + xc * 8;
      const float* pb = x + (size_t)(row0 + xr + 32) * KIN + (it + 1) * 64 + xc * 8;
      xa0 = *(const float4*)pa; xa1 = *(const float4*)(pa + 4);
      xb0 = *(const float4*)pb; xb1 = *(const float4*)(pb + 4);
#pragma unroll
      for (int i = 0; i < 4; ++i) {
        const int v = t + i * 256;
        const int col = v >> 3, c = v & 7;
        wh_[i] = *(const bf16x8*)(whT + (size_t)col * KIN + (it + 1) * 64 + c * 8);
        wl_[i] = *(const bf16x8*)(wloT + (size_t)col * KIN + (it + 1) * 64 + c * 8);
      }
    }
#pragma unroll
    for (int kk = 0; kk < 2; ++kk) {
      const int kb = kk * 32 + (lane >> 4) * 8;
      bf16x8 ah[2], al[2], bh[4], blo[4];
#pragma unroll
      for (int m = 0; m < 2; ++m) {
        const int r = wm * 32 + m * 16 + (lane & 15);
        ah[m] = *(const bf16x8*)(&axh[r][kb]);
        al[m] = *(const bf16x8*)(&axl[r][kb]);
      }
#pragma unroll
      for (int n = 0; n < 4; ++n) {
        const int cidx = wn * 64 + n * 16 + (lane & 15);
        bh[n]  = *(const bf16x8*)(&bwh[cidx][kb]);
        blo[n] = *(const bf16x8*)(&bwl[cidx][kb]);
      }
#pragma unroll
      for (int m = 0; m < 2; ++m)
#pragma unroll
        for (int n = 0; n < 4; ++n) {
          acc[m][n] = __builtin_amdgcn_mfma_f32_16x16x32_bf16(ah[m], bh[n],  acc[m][n], 0, 0, 0);
          acc[m][n] = __builtin_amdgcn_mfma_f32_16x16x32_bf16(ah[m], blo[n], acc[m][n], 0, 0, 0);
          acc[m][n] = __builtin_amdgcn_mfma_f32_16x16x32_bf16(al[m], bh[n],  acc[m][n], 0, 0, 0);
        }
    }
  }

  // feats epilogue: C frag map col=lane&15, row=(lane>>4)*4+r
#pragma unroll
  for (int m = 0; m < 2; ++m) {
    const int rb = row0 + wm * 32 + m * 16 + (lane >> 4) * 4;
    const int cb = wn * 64 + (lane & 15);
#pragma unroll
    for (int n = 0; n < 4; ++n)
#pragma unroll
      for (int r = 0; r < 4; ++r)
        feats[(size_t)(rb + r) * FO + cb + n * 16] = acc[m][n][r];
  }

  // f1/f2 epilogue: reduce 8-lane groups (threads sharing row xr)
#pragma unroll
  for (int off = 1; off < 8; off <<= 1) {
    d1a += __shfl_xor(d1a, off, 64);
    d2a += __shfl_xor(d2a, off, 64);
    d1b += __shfl_xor(d1b, off, 64);
    d2b += __shfl_xor(d2b, off, 64);
  }
  if ((t & 7) == 0) {
    const float bl = blp[0], br = brp[0];
    f1g[row0 + xr] = d1a + bl;
    f2g[row0 + xr] = d2a + br;
    f1g[row0 + xr + 32] = d1b + bl;
    f2g[row0 + xr + 32] = d2b + br;
  }
}

// ---------------- Kernel 3a: hierarchical bitonic sorts + scans -------------
__global__ __launch_bounds__(1024, 1) void k3a_sort(const float* __restrict__ f1g,
                                                    const float* __restrict__ f2g,
                                                    float* __restrict__ f1sort,
                                                    float* __restrict__ sc1,
                                                    float* __restrict__ sc2,
                                                    float* __restrict__ f2sort,
                                                    int* __restrict__ jidxS) {
  __shared__ u64 lds[NN];          // 32 KiB
  __shared__ float wsumA[16], wsumB[16];
  const int t = threadIdx.x;
  const int lane = t & 63, wv = t >> 6;
  const int b = blockIdx.x & 3;
  const int task = blockIdx.x >> 2;
  const int base = b * NN;
  const float* __restrict__ src = task ? f2g : f1g;

  u64 e[4];
#pragma unroll
  for (int r = 0; r < 4; ++r) {
    const int i = 4 * t + r;
    e[r] = ((u64)f2key(src[base + i]) << 32) | (u32)i;
  }

  for (int k = 2; k <= 256; k <<= 1) reg_session(e, t, k);
#pragma unroll
  for (int r = 0; r < 4; ++r) lds[4 * t + r] = e[r];
  __syncthreads();

  for (int k = 512; k <= NN; k <<= 1) {
    for (int j = k >> 1; j >= 256; j >>= 1) {
#pragma unroll
      for (int pp = 0; pp < 2; ++pp) {
        const int p = t + pp * 1024;
        const int i = ((p & ~(j - 1)) << 1) | (p & (j - 1));
        const int ix = i | j;
        const bool up = ((i & k) == 0);
        const u64 a = lds[i], c = lds[ix];
        if ((a > c) == up) { lds[i] = c; lds[ix] = a; }
      }
      __syncthreads();
    }
#pragma unroll
    for (int r = 0; r < 4; ++r) e[r] = lds[4 * t + r];
    reg_session(e, t, k);
    if (k < NN) {
#pragma unroll
      for (int r = 0; r < 4; ++r) lds[4 * t + r] = e[r];
      __syncthreads();
    }
  }

  if (task == 0) {
    float kf[4], a[4], c[4];
#pragma unroll
    for (int r = 0; r < 4; ++r) {
      kf[r] = key2f((u32)(e[r] >> 32));
      f1sort[base + 4 * t + r] = kf[r];
      a[r] = expf(kf[r]);
      c[r] = expf(SLOPE * kf[r]);
    }
#pragma unroll
    for (int r = 1; r < 4; ++r) { a[r] += a[r - 1]; c[r] += c[r - 1]; }
    const float sa = a[3], sb = c[3];
    float pa = sa, pb = sb;
    for (int off = 1; off < 64; off <<= 1) {
      const float oa = __shfl_up(pa, off, 64);
      const float ob = __shfl_up(pb, off, 64);
      if (lane >= off) { pa += oa; pb += ob; }
    }
    if (lane == 63) { wsumA[wv] = pa; wsumB[wv] = pb; }
    __syncthreads();
    float wpa = 0.f, wpb = 0.f;
    for (int w2 = 0; w2 < wv; ++w2) { wpa += wsumA[w2]; wpb += wsumB[w2]; }
    const float basea = wpa + pa - sa, baseb = wpb + pb - sb;
#pragma unroll
    for (int r = 0; r < 4; ++r) {
      sc1[base + 4 * t + r] = basea + a[r];
      sc2[base + 4 * t + r] = baseb + c[r];
    }
  } else {
#pragma unroll
    for (int r = 0; r < 4; ++r) {
      f2sort[base + 4 * t + r] = key2f((u32)(e[r] >> 32));
      jidxS[base + 4 * t + r]  = (int)(e[r] & 0xffffffffu);
    }
  }
}

// ---------------- Kernel 3b: alpha/beta per sorted-j, kpos/E1/E2 per row ----
__global__ __launch_bounds__(512) void k3b_ab(const float* __restrict__ f1sort,
                                              const float* __restrict__ sc1,
                                              const float* __restrict__ sc2,
                                              const float* __restrict__ f2sort,
                                              const float* __restrict__ f1g,
                                              float* __restrict__ alphaS,
                                              float* __restrict__ betaS,
                                              int* __restrict__ kposA,
                                              float* __restrict__ E1g,
                                              float* __restrict__ E2g) {
  __shared__ float s_f1[NN];  // 16 KiB
  __shared__ float s_f2[NN];  // 16 KiB
  const int b = blockIdx.x >> 3;
  const int part = blockIdx.x & 7;
  const int base = b * NN;
  for (int i = threadIdx.x; i < NN; i += 512) {
    s_f1[i] = f1sort[base + i];
    s_f2[i] = f2sort[base + i];
  }
  __syncthreads();
  const int g = part * 512 + threadIdx.x;
  const float T1 = sc1[base + NN - 1];
  const float f1max = s_f1[NN - 1];
  {
    const float f2v = s_f2[g];
    const float m = f1max + f2v;
    const float M = (m >= 0.f) ? m : SLOPE * m;      // column max of leaky scores
    const int p = lower_bound_s(s_f1, NN, -f2v);     // first i with f1 >= -f2
    const float S1 = T1 - (p > 0 ? sc1[base + p - 1] : 0.f);
    const float S2 = (p > 0 ? sc2[base + p - 1] : 0.f);
    const float ea = expf(f2v - M);
    const float eb = expf(SLOPE * f2v - M);
    const float invD = 1.0f / (ea * S1 + eb * S2);
    alphaS[base + g] = ea * invD;
    betaS[base + g]  = eb * invD;
  }
  {
    const float f1v = f1g[base + g];
    kposA[base + g] = lower_bound_s(s_f2, NN, -f1v); // first sorted-j with f2 >= -f1
    E1g[base + g] = expf(f1v);
    E2g[base + g] = expf(SLOPE * f1v);
  }
}

// ---------------- Kernel 4a: per-position inclusive prefixes ----------------
// grid NB*NCC x 128 (chunk = 32 positions -> 512 blocks, 2/CU).
__global__ __launch_bounds__(128) void k4a_pref(const float* __restrict__ feats,
                                                const float* __restrict__ alphaS,
                                                const float* __restrict__ betaS,
                                                const int* __restrict__ jidxS,
                                                float* __restrict__ finePreA,
                                                float* __restrict__ finePreB) {
  const int b = blockIdx.x >> 7, cc = blockIdx.x & 127;
  const int o = threadIdx.x;
  const int base = b * NN + cc * CH;
  const float* fb = feats + (size_t)b * NN * FO;
  float accA = 0.f, accB = 0.f;
#pragma unroll 8
  for (int q = 0; q < CH; ++q) {
    const int kk = base + q;
    const int j = jidxS[kk];
    const float fv = fb[(size_t)j * FO + o];
    accA = fmaf(alphaS[kk], fv, accA);
    accB = fmaf(betaS[kk], fv, accB);
    finePreA[(size_t)kk * FO + o] = accA;
    finePreB[(size_t)kk * FO + o] = accB;
  }
}

// ---------------- Kernel 4c: exclusive prefix over chunk sums ---------------
__global__ __launch_bounds__(128) void k4c_coar(const float* __restrict__ finePreA,
                                                const float* __restrict__ finePreB,
                                                float* __restrict__ coarA,
                                                float* __restrict__ coarB) {
  const int b = blockIdx.x;
  const int o = threadIdx.x;
  float runA = 0.f, runB = 0.f;
#pragma unroll 8
  for (int c = 0; c < NCC; ++c) {
    coarA[(size_t)(b * (NCC + 1) + c) * FO + o] = runA;
    coarB[(size_t)(b * (NCC + 1) + c) * FO + o] = runB;
    runA += finePreA[(size_t)(b * NN + c * CH + CH - 1) * FO + o];
    runB += finePreB[(size_t)(b * NN + c * CH + CH - 1) * FO + o];
  }
  coarA[(size_t)(b * (NCC + 1) + NCC) * FO + o] = runA;   // total
  coarB[(size_t)(b * (NCC + 1) + NCC) * FO + o] = runB;
}

// ---------------- Kernel 5: streaming combine, float4-vectorized ------------
// grid NROW/8 x 256; row per 32 lanes, 4 cols per thread.
__global__ __launch_bounds__(256) void k5_out(const float* __restrict__ finePreA,
                                              const float* __restrict__ finePreB,
                                              const float* __restrict__ coarA,
                                              const float* __restrict__ coarB,
                                              const int* __restrict__ kposA,
                                              const float* __restrict__ E1g,
                                              const float* __restrict__ E2g,
                                              float* __restrict__ out) {
  const int t = threadIdx.x;
  const int row = blockIdx.x * 8 + (t >> 5);
  const int o4 = t & 31;               // float4 index within the 128-col row
  const int b = row >> 12;  // NN = 4096
  const int kp = kposA[row];
  const float e1 = E1g[row], e2 = E2g[row];
  const int c = kp >> 5;               // chunk of 32 (c == NCC when kp == NN)

  const float4* cA = (const float4*)coarA;
  const float4* cB = (const float4*)coarB;
  float4 runA = cA[(size_t)(b * (NCC + 1) + c) * 32 + o4];
  float4 runB = cB[(size_t)(b * (NCC + 1) + c) * 32 + o4];
  const float4 totA = cA[(size_t)(b * (NCC + 1) + NCC) * 32 + o4];
  if (kp & 31) {
    const float4 fA = ((const float4*)finePreA)[(size_t)(b * NN + kp - 1) * 32 + o4];
    const float4 fB = ((const float4*)finePreB)[(size_t)(b * NN + kp - 1) * 32 + o4];
    runA.x += fA.x; runA.y += fA.y; runA.z += fA.z; runA.w += fA.w;
    runB.x += fB.x; runB.y += fB.y; runB.z += fB.z; runB.w += fB.w;
  }
  float4 r;
  r.x = fmaf(e1, totA.x - runA.x, e2 * runB.x);
  r.y = fmaf(e1, totA.y - runA.y, e2 * runB.y);
  r.z = fmaf(e1, totA.z - runA.z, e2 * runB.z);
  r.w = fmaf(e1, totA.w - runA.w, e2 * runB.w);
  ((float4*)out)[(size_t)row * 32 + o4] = r;
}

extern "C" void kernel_launch(void* const* d_in, const int* in_sizes, int n_in,
                              void* d_out, int out_size, void* d_ws, size_t ws_size,
                              hipStream_t stream) {
  const float* x  = (const float*)d_in[0];
  const float* W  = (const float*)d_in[1];
  const float* wl = (const float*)d_in[2];
  const float* bl = (const float*)d_in[3];
  const float* wr = (const float*)d_in[4];
  const float* br = (const float*)d_in[5];
  float* out = (float*)d_out;

  float* ws = (float*)d_ws;
  float* feats    = ws; ws += NROW * FO;
  float* finePreA = ws; ws += NROW * FO;
  float* finePreB = ws; ws += NROW * FO;
  float* f1g      = ws; ws += NROW;
  float* f2g      = ws; ws += NROW;
  float* f1sort   = ws; ws += NROW;
  float* f2sort   = ws; ws += NROW;
  float* sc1      = ws; ws += NROW;
  float* sc2      = ws; ws += NROW;
  float* alphaS   = ws; ws += NROW;
  float* betaS    = ws; ws += NROW;
  float* E1g      = ws; ws += NROW;
  float* E2g      = ws; ws += NROW;
  int* jidxS      = (int*)ws; ws += NROW;
  int* kposA      = (int*)ws; ws += NROW;
  float* coarA    = ws; ws += NB * (NCC + 1) * FO;
  float* coarB    = ws; ws += NB * (NCC + 1) * FO;
  float* u_l      = ws; ws += KIN;
  float* u_r      = ws; ws += KIN;
  u16* whT  = (u16*)ws; ws += FO * KIN / 2;     // bf16 [128 col][256 k]
  u16* wloT = (u16*)ws; ws += FO * KIN / 2;
  (void)in_sizes; (void)n_in; (void)out_size; (void)ws_size;

  hipLaunchKernelGGL(k0_prep,  dim3(128),       dim3(256),  0, stream,
                     W, wl, wr, u_l, u_r, whT, wloT);
  hipLaunchKernelGGL(k1_fused, dim3(NROW / 64), dim3(256),  0, stream,
                     x, whT, wloT, u_l, u_r, bl, br, feats, f1g, f2g);
  hipLaunchKernelGGL(k3a_sort, dim3(8),         dim3(1024), 0, stream,
                     f1g, f2g, f1sort, sc1, sc2, f2sort, jidxS);
  hipLaunchKernelGGL(k3b_ab,   dim3(NB * 8),    dim3(512),  0, stream,
                     f1sort, sc1, sc2, f2sort, f1g, alphaS, betaS, kposA, E1g, E2g);
  hipLaunchKernelGGL(k4a_pref, dim3(NB * NCC),  dim3(128),  0, stream,
                     feats, alphaS, betaS, jidxS, finePreA, finePreB);
  hipLaunchKernelGGL(k4c_coar, dim3(NB),        dim3(128),  0, stream,
                     finePreA, finePreB, coarA, coarB);
  hipLaunchKernelGGL(k5_out,   dim3(NROW / 8),  dim3(256),  0, stream,
                     finePreA, finePreB, coarA, coarB, kposA, E1g, E2g, out);
}

// Round 15
// 68.500 us; speedup vs baseline: 1.1127x; 1.0236x over previous
//
#include <hip/hip_runtime.h>

using u16 = unsigned short;
using u32 = unsigned int;
using u64 = unsigned long long;

typedef short bf16x8 __attribute__((ext_vector_type(8)));
typedef float f32x4 __attribute__((ext_vector_type(4)));

static constexpr int NB  = 4;     // batch
static constexpr int NN  = 4096;  // nodes
static constexpr int KIN = 256;   // in features
static constexpr int FO  = 128;   // out features
static constexpr int NROW = NB * NN;  // 16384 total rows
static constexpr int NCC = 64;    // coarse chunks per batch (64 positions each)
static constexpr float SLOPE = 0.01f;

// ---- bf16 helpers (RNE, no NaN inputs) ----
__device__ __forceinline__ u16 f2bf(float f) {
  const u32 u = __float_as_uint(f);
  return (u16)((u + 0x7fffu + ((u >> 16) & 1u)) >> 16);
}
__device__ __forceinline__ float bf2f(u16 h) {
  return __uint_as_float(((u32)h) << 16);
}
__device__ __forceinline__ float dot4(const float4& a, const float4& b) {
  return a.x * b.x + a.y * b.y + a.z * b.z + a.w * b.w;
}

// monotone bijection f32 -> orderable u32 (no NaNs present)
__device__ __forceinline__ u32 f2key(float f) {
  const u32 b = __float_as_uint(f);
  return (b & 0x80000000u) ? ~b : (b | 0x80000000u);
}
__device__ __forceinline__ float key2f(u32 u) {
  const u32 b = (u & 0x80000000u) ? (u ^ 0x80000000u) : ~u;
  return __uint_as_float(b);
}

__device__ __forceinline__ u64 shfl_xor64(u64 v, int m) {
  const u32 lo = __shfl_xor((u32)(v & 0xffffffffu), m, 64);
  const u32 hi = __shfl_xor((u32)(v >> 32), m, 64);
  return ((u64)hi << 32) | (u64)lo;
}
__device__ __forceinline__ void cswap(u64& a, u64& b, bool up) {
  if ((a > b) == up) { const u64 tmp = a; a = b; b = tmp; }
}

// bitonic rounds j = min(k/2,128)..1 for phase k, data in registers.
__device__ __forceinline__ void reg_session(u64 e[4], int t, int k) {
  const int jstart = (k > 256) ? 128 : (k >> 1);
  for (int j = jstart; j >= 4; j >>= 1) {
    const int J = j >> 2;
    const bool up   = ((t & (k >> 2)) == 0);
    const bool lowr = ((t & J) == 0);
#pragma unroll
    for (int r = 0; r < 4; ++r) {
      const u64 o = shfl_xor64(e[r], J);
      const bool less = e[r] < o;              // keys unique (idx tie-break)
      e[r] = ((lowr == up) == less) ? e[r] : o;
    }
  }
  if (k >= 4) {
    const bool up = ((t & (k >> 2)) == 0);
    cswap(e[0], e[2], up); cswap(e[1], e[3], up);
  }
  {
    const bool up0 = (((4 * t)     & k) == 0);
    const bool up1 = (((4 * t + 2) & k) == 0);
    cswap(e[0], e[1], up0); cswap(e[2], e[3], up1);
  }
}

__device__ __forceinline__ int lower_bound_s(const float* a, int n, float t) {
  int lo = 0, hi = n;
  while (lo < hi) {
    const int mid = (lo + hi) >> 1;
    if (a[mid] < t) lo = mid + 1; else hi = mid;
  }
  return lo;
}

// ---------------- Kernel 0: u = W @ w, Wh/Wl bf16 split transposed ---------
__global__ __launch_bounds__(256) void k0_prep(const float* __restrict__ W,
                                               const float* __restrict__ wl,
                                               const float* __restrict__ wr,
                                               float* __restrict__ u_l,
                                               float* __restrict__ u_r,
                                               u16* __restrict__ whT,
                                               u16* __restrict__ wloT) {
  const int t = threadIdx.x;
  const int blk = blockIdx.x;
  if (blk < 64) {
    const int k = blk * 4 + (t >> 6);
    const int lane = t & 63;
    const float w0 = W[k * FO + lane], w1 = W[k * FO + 64 + lane];
    float a1 = w0 * wl[lane] + w1 * wl[64 + lane];
    float a2 = w0 * wr[lane] + w1 * wr[64 + lane];
#pragma unroll
    for (int off = 1; off < 64; off <<= 1) {
      a1 += __shfl_xor(a1, off, 64);
      a2 += __shfl_xor(a2, off, 64);
    }
    if (lane == 0) { u_l[k] = a1; u_r[k] = a2; }
  } else {
#pragma unroll
    for (int e = 0; e < 2; ++e) {
      const int idx = (blk - 64) * 512 + t + e * 256;  // 0..32767
      const int col = idx >> 8, k = idx & 255;
      const float v = W[k * FO + col];
      const u16 h = f2bf(v);
      whT[col * KIN + k]  = h;
      wloT[col * KIN + k] = f2bf(v - bf2f(h));
    }
  }
}

// ---------------- Kernel 1: fused x-load -> f1/f2 + split-bf16 MFMA feats --
// grid 512 x 256. BM=32, BN=128, BK=64; 4 waves 1x4 (wave-tile 32x32);
// 46 KB LDS -> 2 blocks/CU, 8 waves/CU (2x R8 occupancy).
__global__ __launch_bounds__(256) void k1_fused(const float* __restrict__ x,
                                                const u16* __restrict__ whT,
                                                const u16* __restrict__ wloT,
                                                const float* __restrict__ u_l,
                                                const float* __restrict__ u_r,
                                                const float* __restrict__ blp,
                                                const float* __restrict__ brp,
                                                float* __restrict__ feats,
                                                float* __restrict__ f1g,
                                                float* __restrict__ f2g) {
  __shared__ u16 axh[32][72];
  __shared__ u16 axl[32][72];
  __shared__ u16 bwh[128][72];
  __shared__ u16 bwl[128][72];
  const int t = threadIdx.x;
  const int wn = t >> 6, lane = t & 63;    // wave = col quarter
  const int row0 = blockIdx.x * 32;
  const int xr = t >> 3, xc = t & 7;       // x staging: row xr, k-chunk xc
  f32x4 acc[2][2];
#pragma unroll
  for (int m = 0; m < 2; ++m)
#pragma unroll
    for (int n = 0; n < 2; ++n) acc[m][n] = (f32x4)0.f;

  float d1a = 0.f, d2a = 0.f;              // f1/f2 partials (row xr)
  float4 xa0, xa1;
  bf16x8 wh_[4], wl_[4];

  // prologue prefetch (it = 0)
  {
    const float* pa = x + (size_t)(row0 + xr) * KIN + xc * 8;
    xa0 = *(const float4*)pa; xa1 = *(const float4*)(pa + 4);
#pragma unroll
    for (int i = 0; i < 4; ++i) {
      const int v = t + i * 256;
      const int col = v >> 3, c = v & 7;
      wh_[i] = *(const bf16x8*)(whT + (size_t)col * KIN + c * 8);
      wl_[i] = *(const bf16x8*)(wloT + (size_t)col * KIN + c * 8);
    }
  }

  for (int it = 0; it < 4; ++it) {
    if (it) __syncthreads();   // previous compute done before overwrite
    {
      const float4 ul0 = *(const float4*)(u_l + it * 64 + xc * 8);
      const float4 ul1 = *(const float4*)(u_l + it * 64 + xc * 8 + 4);
      const float4 ur0 = *(const float4*)(u_r + it * 64 + xc * 8);
      const float4 ur1 = *(const float4*)(u_r + it * 64 + xc * 8 + 4);
      d1a += dot4(xa0, ul0) + dot4(xa1, ul1);
      d2a += dot4(xa0, ur0) + dot4(xa1, ur1);
    }
    {
      float va[8] = {xa0.x, xa0.y, xa0.z, xa0.w, xa1.x, xa1.y, xa1.z, xa1.w};
      bf16x8 ha, la;
#pragma unroll
      for (int q = 0; q < 8; ++q) {
        const u16 h1 = f2bf(va[q]);
        ha[q] = (short)h1; la[q] = (short)f2bf(va[q] - bf2f(h1));
      }
      *(bf16x8*)(&axh[xr][xc * 8]) = ha;
      *(bf16x8*)(&axl[xr][xc * 8]) = la;
    }
#pragma unroll
    for (int i = 0; i < 4; ++i) {
      const int v = t + i * 256;
      const int col = v >> 3, c = v & 7;
      *(bf16x8*)(&bwh[col][c * 8]) = wh_[i];
      *(bf16x8*)(&bwl[col][c * 8]) = wl_[i];
    }
    __syncthreads();
    if (it < 3) {
      const float* pa = x + (size_t)(row0 + xr) * KIN + (it + 1) * 64 + xc * 8;
      xa0 = *(const float4*)pa; xa1 = *(const float4*)(pa + 4);
#pragma unroll
      for (int i = 0; i < 4; ++i) {
        const int v = t + i * 256;
        const int col = v >> 3, c = v & 7;
        wh_[i] = *(const bf16x8*)(whT + (size_t)col * KIN + (it + 1) * 64 + c * 8);
        wl_[i] = *(const bf16x8*)(wloT + (size_t)col * KIN + (it + 1) * 64 + c * 8);
      }
    }
#pragma unroll
    for (int kk = 0; kk < 2; ++kk) {
      const int kb = kk * 32 + (lane >> 4) * 8;
      bf16x8 ah[2], al[2], bh[2], blo[2];
#pragma unroll
      for (int m = 0; m < 2; ++m) {
        const int r = m * 16 + (lane & 15);
        ah[m] = *(const bf16x8*)(&axh[r][kb]);
        al[m] = *(const bf16x8*)(&axl[r][kb]);
      }
#pragma unroll
      for (int n = 0; n < 2; ++n) {
        const int cidx = wn * 32 + n * 16 + (lane & 15);
        bh[n]  = *(const bf16x8*)(&bwh[cidx][kb]);
        blo[n] = *(const bf16x8*)(&bwl[cidx][kb]);
      }
#pragma unroll
      for (int m = 0; m < 2; ++m)
#pragma unroll
        for (int n = 0; n < 2; ++n) {
          acc[m][n] = __builtin_amdgcn_mfma_f32_16x16x32_bf16(ah[m], bh[n],  acc[m][n], 0, 0, 0);
          acc[m][n] = __builtin_amdgcn_mfma_f32_16x16x32_bf16(ah[m], blo[n], acc[m][n], 0, 0, 0);
          acc[m][n] = __builtin_amdgcn_mfma_f32_16x16x32_bf16(al[m], bh[n],  acc[m][n], 0, 0, 0);
        }
    }
  }

  // feats epilogue: C frag map col=lane&15, row=(lane>>4)*4+r
#pragma unroll
  for (int m = 0; m < 2; ++m) {
    const int rb = row0 + m * 16 + (lane >> 4) * 4;
    const int cb = wn * 32 + (lane & 15);
#pragma unroll
    for (int n = 0; n < 2; ++n)
#pragma unroll
      for (int r = 0; r < 4; ++r)
        feats[(size_t)(rb + r) * FO + cb + n * 16] = acc[m][n][r];
  }

  // f1/f2 epilogue: reduce 8-lane groups (threads sharing row xr)
#pragma unroll
  for (int off = 1; off < 8; off <<= 1) {
    d1a += __shfl_xor(d1a, off, 64);
    d2a += __shfl_xor(d2a, off, 64);
  }
  if ((t & 7) == 0) {
    f1g[row0 + xr] = d1a + blp[0];
    f2g[row0 + xr] = d2a + brp[0];
  }
}

// ---------------- Kernel 3a: hierarchical bitonic sorts + scans -------------
__global__ __launch_bounds__(1024, 1) void k3a_sort(const float* __restrict__ f1g,
                                                    const float* __restrict__ f2g,
                                                    float* __restrict__ f1sort,
                                                    float* __restrict__ sc1,
                                                    float* __restrict__ sc2,
                                                    float* __restrict__ f2sort,
                                                    int* __restrict__ jidxS) {
  __shared__ u64 lds[NN];          // 32 KiB
  __shared__ float wsumA[16], wsumB[16];
  const int t = threadIdx.x;
  const int lane = t & 63, wv = t >> 6;
  const int b = blockIdx.x & 3;
  const int task = blockIdx.x >> 2;
  const int base = b * NN;
  const float* __restrict__ src = task ? f2g : f1g;

  u64 e[4];
#pragma unroll
  for (int r = 0; r < 4; ++r) {
    const int i = 4 * t + r;
    e[r] = ((u64)f2key(src[base + i]) << 32) | (u32)i;
  }

  for (int k = 2; k <= 256; k <<= 1) reg_session(e, t, k);
#pragma unroll
  for (int r = 0; r < 4; ++r) lds[4 * t + r] = e[r];
  __syncthreads();

  for (int k = 512; k <= NN; k <<= 1) {
    for (int j = k >> 1; j >= 256; j >>= 1) {
#pragma unroll
      for (int pp = 0; pp < 2; ++pp) {
        const int p = t + pp * 1024;
        const int i = ((p & ~(j - 1)) << 1) | (p & (j - 1));
        const int ix = i | j;
        const bool up = ((i & k) == 0);
        const u64 a = lds[i], c = lds[ix];
        if ((a > c) == up) { lds[i] = c; lds[ix] = a; }
      }
      __syncthreads();
    }
#pragma unroll
    for (int r = 0; r < 4; ++r) e[r] = lds[4 * t + r];
    reg_session(e, t, k);
    if (k < NN) {
#pragma unroll
      for (int r = 0; r < 4; ++r) lds[4 * t + r] = e[r];
      __syncthreads();
    }
  }

  if (task == 0) {
    float kf[4], a[4], c[4];
#pragma unroll
    for (int r = 0; r < 4; ++r) {
      kf[r] = key2f((u32)(e[r] >> 32));
      f1sort[base + 4 * t + r] = kf[r];
      a[r] = expf(kf[r]);
      c[r] = expf(SLOPE * kf[r]);
    }
#pragma unroll
    for (int r = 1; r < 4; ++r) { a[r] += a[r - 1]; c[r] += c[r - 1]; }
    const float sa = a[3], sb = c[3];
    float pa = sa, pb = sb;
    for (int off = 1; off < 64; off <<= 1) {
      const float oa = __shfl_up(pa, off, 64);
      const float ob = __shfl_up(pb, off, 64);
      if (lane >= off) { pa += oa; pb += ob; }
    }
    if (lane == 63) { wsumA[wv] = pa; wsumB[wv] = pb; }
    __syncthreads();
    float wpa = 0.f, wpb = 0.f;
    for (int w2 = 0; w2 < wv; ++w2) { wpa += wsumA[w2]; wpb += wsumB[w2]; }
    const float basea = wpa + pa - sa, baseb = wpb + pb - sb;
#pragma unroll
    for (int r = 0; r < 4; ++r) {
      sc1[base + 4 * t + r] = basea + a[r];
      sc2[base + 4 * t + r] = baseb + c[r];
    }
  } else {
#pragma unroll
    for (int r = 0; r < 4; ++r) {
      f2sort[base + 4 * t + r] = key2f((u32)(e[r] >> 32));
      jidxS[base + 4 * t + r]  = (int)(e[r] & 0xffffffffu);
    }
  }
}

// ---------------- Kernel 3b: alpha/beta per sorted-j, kpos/E1/E2 per row ----
__global__ __launch_bounds__(512) void k3b_ab(const float* __restrict__ f1sort,
                                              const float* __restrict__ sc1,
                                              const float* __restrict__ sc2,
                                              const float* __restrict__ f2sort,
                                              const float* __restrict__ f1g,
                                              float* __restrict__ alphaS,
                                              float* __restrict__ betaS,
                                              int* __restrict__ kposA,
                                              float* __restrict__ E1g,
                                              float* __restrict__ E2g) {
  __shared__ float s_f1[NN];  // 16 KiB
  __shared__ float s_f2[NN];  // 16 KiB
  const int b = blockIdx.x >> 3;
  const int part = blockIdx.x & 7;
  const int base = b * NN;
  for (int i = threadIdx.x; i < NN; i += 512) {
    s_f1[i] = f1sort[base + i];
    s_f2[i] = f2sort[base + i];
  }
  __syncthreads();
  const int g = part * 512 + threadIdx.x;
  const float T1 = sc1[base + NN - 1];
  const float f1max = s_f1[NN - 1];
  {
    const float f2v = s_f2[g];
    const float m = f1max + f2v;
    const float M = (m >= 0.f) ? m : SLOPE * m;      // column max of leaky scores
    const int p = lower_bound_s(s_f1, NN, -f2v);     // first i with f1 >= -f2
    const float S1 = T1 - (p > 0 ? sc1[base + p - 1] : 0.f);
    const float S2 = (p > 0 ? sc2[base + p - 1] : 0.f);
    const float ea = expf(f2v - M);
    const float eb = expf(SLOPE * f2v - M);
    const float invD = 1.0f / (ea * S1 + eb * S2);
    alphaS[base + g] = ea * invD;
    betaS[base + g]  = eb * invD;
  }
  {
    const float f1v = f1g[base + g];
    kposA[base + g] = lower_bound_s(s_f2, NN, -f1v); // first sorted-j with f2 >= -f1
    E1g[base + g] = expf(f1v);
    E2g[base + g] = expf(SLOPE * f1v);
  }
}

// ---------------- Kernel 4a: per-position inclusive prefixes ----------------
__global__ __launch_bounds__(128) void k4a_pref(const float* __restrict__ feats,
                                                const float* __restrict__ alphaS,
                                                const float* __restrict__ betaS,
                                                const int* __restrict__ jidxS,
                                                float* __restrict__ finePreA,
                                                float* __restrict__ finePreB) {
  const int b = blockIdx.x >> 6, cc = blockIdx.x & 63;
  const int o = threadIdx.x;
  const int base = b * NN + cc * 64;
  const float* fb = feats + (size_t)b * NN * FO;
  float accA = 0.f, accB = 0.f;
#pragma unroll 8
  for (int q = 0; q < 64; ++q) {
    const int kk = base + q;
    const int j = jidxS[kk];
    const float fv = fb[(size_t)j * FO + o];
    accA = fmaf(alphaS[kk], fv, accA);
    accB = fmaf(betaS[kk], fv, accB);
    finePreA[(size_t)kk * FO + o] = accA;
    finePreB[(size_t)kk * FO + o] = accB;
  }
}

// ---------------- Kernel 4c: exclusive prefix over coarse sums --------------
__global__ __launch_bounds__(128) void k4c_coar(const float* __restrict__ finePreA,
                                                const float* __restrict__ finePreB,
                                                float* __restrict__ coarA,
                                                float* __restrict__ coarB) {
  const int b = blockIdx.x;
  const int o = threadIdx.x;
  float runA = 0.f, runB = 0.f;
#pragma unroll
  for (int c = 0; c < NCC; ++c) {
    coarA[(size_t)(b * (NCC + 1) + c) * FO + o] = runA;
    coarB[(size_t)(b * (NCC + 1) + c) * FO + o] = runB;
    runA += finePreA[(size_t)(b * NN + c * 64 + 63) * FO + o];
    runB += finePreB[(size_t)(b * NN + c * 64 + 63) * FO + o];
  }
  coarA[(size_t)(b * (NCC + 1) + NCC) * FO + o] = runA;   // total
  coarB[(size_t)(b * (NCC + 1) + NCC) * FO + o] = runB;
}

// ---------------- Kernel 5: streaming combine (no gathers) ------------------
__global__ __launch_bounds__(256) void k5_out(const float* __restrict__ finePreA,
                                              const float* __restrict__ finePreB,
                                              const float* __restrict__ coarA,
                                              const float* __restrict__ coarB,
                                              const int* __restrict__ kposA,
                                              const float* __restrict__ E1g,
                                              const float* __restrict__ E2g,
                                              float* __restrict__ out) {
  const int t = threadIdx.x;
  const int row = blockIdx.x * 2 + (t >> 7);
  const int o = t & 127;
  const int b = row >> 12;  // NN = 4096
  const int kp = kposA[row];
  const float e1 = E1g[row], e2 = E2g[row];
  const int c = kp >> 6;          // 0..64

  float runA = coarA[(size_t)(b * (NCC + 1) + c) * FO + o];
  float runB = coarB[(size_t)(b * (NCC + 1) + c) * FO + o];
  const float totA = coarA[(size_t)(b * (NCC + 1) + NCC) * FO + o];
  if (kp & 63) {
    runA += finePreA[(size_t)(b * NN + kp - 1) * FO + o];
    runB += finePreB[(size_t)(b * NN + kp - 1) * FO + o];
  }
  out[(size_t)row * FO + o] = fmaf(e1, totA - runA, e2 * runB);
}

extern "C" void kernel_launch(void* const* d_in, const int* in_sizes, int n_in,
                              void* d_out, int out_size, void* d_ws, size_t ws_size,
                              hipStream_t stream) {
  const float* x  = (const float*)d_in[0];
  const float* W  = (const float*)d_in[1];
  const float* wl = (const float*)d_in[2];
  const float* bl = (const float*)d_in[3];
  const float* wr = (const float*)d_in[4];
  const float* br = (const float*)d_in[5];
  float* out = (float*)d_out;

  float* ws = (float*)d_ws;
  float* feats    = ws; ws += NROW * FO;
  float* finePreA = ws; ws += NROW * FO;
  float* finePreB = ws; ws += NROW * FO;
  float* f1g      = ws; ws += NROW;
  float* f2g      = ws; ws += NROW;
  float* f1sort   = ws; ws += NROW;
  float* f2sort   = ws; ws += NROW;
  float* sc1      = ws; ws += NROW;
  float* sc2      = ws; ws += NROW;
  float* alphaS   = ws; ws += NROW;
  float* betaS    = ws; ws += NROW;
  float* E1g      = ws; ws += NROW;
  float* E2g      = ws; ws += NROW;
  int* jidxS      = (int*)ws; ws += NROW;
  int* kposA      = (int*)ws; ws += NROW;
  float* coarA    = ws; ws += NB * (NCC + 1) * FO;
  float* coarB    = ws; ws += NB * (NCC + 1) * FO;
  float* u_l      = ws; ws += KIN;
  float* u_r      = ws; ws += KIN;
  u16* whT  = (u16*)ws; ws += FO * KIN / 2;     // bf16 [128 col][256 k]
  u16* wloT = (u16*)ws; ws += FO * KIN / 2;
  (void)in_sizes; (void)n_in; (void)out_size; (void)ws_size;

  hipLaunchKernelGGL(k0_prep,  dim3(128),       dim3(256),  0, stream,
                     W, wl, wr, u_l, u_r, whT, wloT);
  hipLaunchKernelGGL(k1_fused, dim3(NROW / 32), dim3(256),  0, stream,
                     x, whT, wloT, u_l, u_r, bl, br, feats, f1g, f2g);
  hipLaunchKernelGGL(k3a_sort, dim3(8),         dim3(1024), 0, stream,
                     f1g, f2g, f1sort, sc1, sc2, f2sort, jidxS);
  hipLaunchKernelGGL(k3b_ab,   dim3(NB * 8),    dim3(512),  0, stream,
                     f1sort, sc1, sc2, f2sort, f1g, alphaS, betaS, kposA, E1g, E2g);
  hipLaunchKernelGGL(k4a_pref, dim3(NB * NCC),  dim3(128),  0, stream,
                     feats, alphaS, betaS, jidxS, finePreA, finePreB);
  hipLaunchKernelGGL(k4c_coar, dim3(NB),        dim3(128),  0, stream,
                     finePreA, finePreB, coarA, coarB);
  hipLaunchKernelGGL(k5_out,   dim3(NROW / 2),  dim3(256),  0, stream,
                     finePreA, finePreB, coarA, coarB, kposA, E1g, E2g, out);
}

// Round 16
// 68.245 us; speedup vs baseline: 1.1169x; 1.0037x over previous
//
#include <hip/hip_runtime.h>

using u16 = unsigned short;
using u32 = unsigned int;
using u64 = unsigned long long;

typedef short bf16x8 __attribute__((ext_vector_type(8)));
typedef float f32x4 __attribute__((ext_vector_type(4)));

static constexpr int NB  = 4;     // batch
static constexpr int NN  = 4096;  // nodes
static constexpr int KIN = 256;   // in features
static constexpr int FO  = 128;   // out features
static constexpr int NROW = NB * NN;  // 16384 total rows
static constexpr int NCC = 64;    // coarse chunks per batch (64 positions each)
static constexpr int NWK = 248;   // persistent GEMM workers in kB
static constexpr float SLOPE = 0.01f;

// ---- bf16 helpers (RNE, no NaN inputs) ----
__device__ __forceinline__ u16 f2bf(float f) {
  const u32 u = __float_as_uint(f);
  return (u16)((u + 0x7fffu + ((u >> 16) & 1u)) >> 16);
}
__device__ __forceinline__ float bf2f(u16 h) {
  return __uint_as_float(((u32)h) << 16);
}
__device__ __forceinline__ float dot4(const float4& a, const float4& b) {
  return a.x * b.x + a.y * b.y + a.z * b.z + a.w * b.w;
}

// monotone bijection f32 -> orderable u32 (no NaNs present)
__device__ __forceinline__ u32 f2key(float f) {
  const u32 b = __float_as_uint(f);
  return (b & 0x80000000u) ? ~b : (b | 0x80000000u);
}
__device__ __forceinline__ float key2f(u32 u) {
  const u32 b = (u & 0x80000000u) ? (u ^ 0x80000000u) : ~u;
  return __uint_as_float(b);
}

__device__ __forceinline__ u64 shfl_xor64(u64 v, int m) {
  const u32 lo = __shfl_xor((u32)(v & 0xffffffffu), m, 64);
  const u32 hi = __shfl_xor((u32)(v >> 32), m, 64);
  return ((u64)hi << 32) | (u64)lo;
}
__device__ __forceinline__ void cswap(u64& a, u64& b, bool up) {
  if ((a > b) == up) { const u64 tmp = a; a = b; b = tmp; }
}

// bitonic rounds j = min(k/2,128)..1 for phase k, data in registers.
__device__ __forceinline__ void reg_session(u64 e[4], int t, int k) {
  const int jstart = (k > 256) ? 128 : (k >> 1);
  for (int j = jstart; j >= 4; j >>= 1) {
    const int J = j >> 2;
    const bool up   = ((t & (k >> 2)) == 0);
    const bool lowr = ((t & J) == 0);
#pragma unroll
    for (int r = 0; r < 4; ++r) {
      const u64 o = shfl_xor64(e[r], J);
      const bool less = e[r] < o;              // keys unique (idx tie-break)
      e[r] = ((lowr == up) == less) ? e[r] : o;
    }
  }
  if (k >= 4) {
    const bool up = ((t & (k >> 2)) == 0);
    cswap(e[0], e[2], up); cswap(e[1], e[3], up);
  }
  {
    const bool up0 = (((4 * t)     & k) == 0);
    const bool up1 = (((4 * t + 2) & k) == 0);
    cswap(e[0], e[1], up0); cswap(e[2], e[3], up1);
  }
}

__device__ __forceinline__ int lower_bound_s(const float* a, int n, float t) {
  int lo = 0, hi = n;
  while (lo < hi) {
    const int mid = (lo + hi) >> 1;
    if (a[mid] < t) lo = mid + 1; else hi = mid;
  }
  return lo;
}

// ---------------- Kernel 0: W split + exact f1/f2 (pre-GEMM) ---------------
// grid 256 x 256. Every block: u_l/u_r in LDS (thread t = k-row), then
// f1/f2 for 64 rows (wave per 16 rows, lane-parallel dot + shfl reduce).
// Blocks 0-63 additionally write the Wh/Wl bf16 transposed split.
__global__ __launch_bounds__(256) void k0_prep(const float* __restrict__ x,
                                               const float* __restrict__ W,
                                               const float* __restrict__ wl,
                                               const float* __restrict__ blp,
                                               const float* __restrict__ wr,
                                               const float* __restrict__ brp,
                                               u16* __restrict__ whT,
                                               u16* __restrict__ wloT,
                                               float* __restrict__ f1g,
                                               float* __restrict__ f2g) {
  __shared__ float uls[KIN];
  __shared__ float urs[KIN];
  const int t = threadIdx.x;
  const int bid = blockIdx.x;

  if (bid < 64) {  // W hi/lo split transpose
#pragma unroll
    for (int e = 0; e < 2; ++e) {
      const int idx = bid * 512 + t + e * 256;  // 0..32767
      const int col = idx >> 8, k = idx & 255;
      const float v = W[k * FO + col];
      const u16 h = f2bf(v);
      whT[col * KIN + k]  = h;
      wloT[col * KIN + k] = f2bf(v - bf2f(h));
    }
  }
  // u_l[k]/u_r[k] for k = t (exact f32 serial dot; W L2-hot)
  {
    const float* Wr = W + (size_t)t * FO;
    float s1 = 0.f, s2 = 0.f;
#pragma unroll 8
    for (int c = 0; c < FO; ++c) {
      const float wv = Wr[c];
      s1 = fmaf(wv, wl[c], s1);
      s2 = fmaf(wv, wr[c], s2);
    }
    uls[t] = s1; urs[t] = s2;
  }
  __syncthreads();
  // f1/f2: wave wv handles 16 rows serially; 64 lanes x float4 covers a row
  const int wv = t >> 6, lane = t & 63;
  const int row0 = bid * 64 + wv * 16;
  const float4 ul = *(const float4*)(&uls[lane * 4]);
  const float4 ur = *(const float4*)(&urs[lane * 4]);
  const float blv = blp[0], brv = brp[0];
  for (int r = 0; r < 16; ++r) {
    const int row = row0 + r;
    const float4 xv = *(const float4*)(x + (size_t)row * KIN + lane * 4);
    float d1 = dot4(xv, ul);
    float d2 = dot4(xv, ur);
#pragma unroll
    for (int off = 1; off < 64; off <<= 1) {
      d1 += __shfl_xor(d1, off, 64);
      d2 += __shfl_xor(d2, off, 64);
    }
    if (lane == 0) { f1g[row] = d1 + blv; f2g[row] = d2 + brv; }
  }
}

// ---------------- Kernel B: sort (blocks 0-7) || persistent MFMA GEMM ------
// grid 256 x 1024. Sort path: R8 k3a verbatim. GEMM path: 248 workers loop
// over 256 tiles (BM=64, 16 waves 4x4, wave-tile 16x32, split-bf16 MFMA).
__global__ __launch_bounds__(1024, 1) void kB_main(const float* __restrict__ x,
                                                   const u16* __restrict__ whT,
                                                   const u16* __restrict__ wloT,
                                                   const float* __restrict__ f1g,
                                                   const float* __restrict__ f2g,
                                                   float* __restrict__ feats,
                                                   float* __restrict__ f1sort,
                                                   float* __restrict__ sc1,
                                                   float* __restrict__ sc2,
                                                   float* __restrict__ f2sort,
                                                   int* __restrict__ jidxS) {
  __shared__ __align__(16) unsigned char smem[55296];
  const int tid = threadIdx.x;
  const int bid = blockIdx.x;

  if (bid < 8) {
    // ======== hierarchical bitonic sort + exp scans (R8 k3a) ========
    u64* lds = (u64*)smem;                  // [4096] = 32 KiB
    float* wsumA = (float*)(smem + 32768);  // [16]
    float* wsumB = (float*)(smem + 32832);  // [16]
    const int t = tid;
    const int lane = t & 63, wv = t >> 6;
    const int b = bid & 3;
    const int task = bid >> 2;
    const int base = b * NN;
    const float* __restrict__ src = task ? f2g : f1g;

    u64 e[4];
#pragma unroll
    for (int r = 0; r < 4; ++r) {
      const int i = 4 * t + r;
      e[r] = ((u64)f2key(src[base + i]) << 32) | (u32)i;
    }
    for (int k = 2; k <= 256; k <<= 1) reg_session(e, t, k);
#pragma unroll
    for (int r = 0; r < 4; ++r) lds[4 * t + r] = e[r];
    __syncthreads();
    for (int k = 512; k <= NN; k <<= 1) {
      for (int j = k >> 1; j >= 256; j >>= 1) {
#pragma unroll
        for (int pp = 0; pp < 2; ++pp) {
          const int pw = t + pp * 1024;
          const int i = ((pw & ~(j - 1)) << 1) | (pw & (j - 1));
          const int ix = i | j;
          const bool up = ((i & k) == 0);
          const u64 a = lds[i], c = lds[ix];
          if ((a > c) == up) { lds[i] = c; lds[ix] = a; }
        }
        __syncthreads();
      }
#pragma unroll
      for (int r = 0; r < 4; ++r) e[r] = lds[4 * t + r];
      reg_session(e, t, k);
      if (k < NN) {
#pragma unroll
        for (int r = 0; r < 4; ++r) lds[4 * t + r] = e[r];
        __syncthreads();
      }
    }
    if (task == 0) {
      float kf[4], a[4], c[4];
#pragma unroll
      for (int r = 0; r < 4; ++r) {
        kf[r] = key2f((u32)(e[r] >> 32));
        f1sort[base + 4 * t + r] = kf[r];
        a[r] = expf(kf[r]);
        c[r] = expf(SLOPE * kf[r]);
      }
#pragma unroll
      for (int r = 1; r < 4; ++r) { a[r] += a[r - 1]; c[r] += c[r - 1]; }
      const float sa = a[3], sb = c[3];
      float pa = sa, pb = sb;
      for (int off = 1; off < 64; off <<= 1) {
        const float oa = __shfl_up(pa, off, 64);
        const float ob = __shfl_up(pb, off, 64);
        if (lane >= off) { pa += oa; pb += ob; }
      }
      if (lane == 63) { wsumA[wv] = pa; wsumB[wv] = pb; }
      __syncthreads();
      float wpa = 0.f, wpb = 0.f;
      for (int w2 = 0; w2 < wv; ++w2) { wpa += wsumA[w2]; wpb += wsumB[w2]; }
      const float basea = wpa + pa - sa, baseb = wpb + pb - sb;
#pragma unroll
      for (int r = 0; r < 4; ++r) {
        sc1[base + 4 * t + r] = basea + a[r];
        sc2[base + 4 * t + r] = baseb + c[r];
      }
    } else {
#pragma unroll
      for (int r = 0; r < 4; ++r) {
        f2sort[base + 4 * t + r] = key2f((u32)(e[r] >> 32));
        jidxS[base + 4 * t + r]  = (int)(e[r] & 0xffffffffu);
      }
    }
  } else {
    // ======== persistent split-bf16 MFMA GEMM (248 workers, 256 tiles) =====
    u16* axh = (u16*)smem;                 // [64][72]
    u16* axl = (u16*)(smem + 9216);
    u16* bwh = (u16*)(smem + 18432);       // [128][72]
    u16* bwl = (u16*)(smem + 36864);
    const int w = tid >> 6, lane = tid & 63;
    const int wm = w >> 2, wn = w & 3;
    const int xr = tid >> 4, xc4 = (tid & 15) * 4;   // x staging: 64r x 16 f4
    const int wcol = tid >> 3, wc = tid & 7;         // W staging: 128c x 8 b8
    bool needSync = false;

    for (int tile = bid - 8; tile < NROW / 64; tile += NWK) {
      const int row0 = tile * 64;
      f32x4 acc[2];
      acc[0] = (f32x4)0.f; acc[1] = (f32x4)0.f;
      float4 xv;
      bf16x8 whb, wlb;
      xv  = *(const float4*)(x + (size_t)(row0 + xr) * KIN + xc4);
      whb = *(const bf16x8*)(whT  + (size_t)wcol * KIN + wc * 8);
      wlb = *(const bf16x8*)(wloT + (size_t)wcol * KIN + wc * 8);

      for (int it = 0; it < 4; ++it) {
        if (it || needSync) __syncthreads();
        {
          float va[4] = {xv.x, xv.y, xv.z, xv.w};
          ushort4 hh, ll;
          const u16 h0 = f2bf(va[0]); hh.x = h0; ll.x = f2bf(va[0] - bf2f(h0));
          const u16 h1 = f2bf(va[1]); hh.y = h1; ll.y = f2bf(va[1] - bf2f(h1));
          const u16 h2 = f2bf(va[2]); hh.z = h2; ll.z = f2bf(va[2] - bf2f(h2));
          const u16 h3 = f2bf(va[3]); hh.w = h3; ll.w = f2bf(va[3] - bf2f(h3));
          *(ushort4*)(&axh[xr * 72 + xc4]) = hh;
          *(ushort4*)(&axl[xr * 72 + xc4]) = ll;
        }
        *(bf16x8*)(&bwh[wcol * 72 + wc * 8]) = whb;
        *(bf16x8*)(&bwl[wcol * 72 + wc * 8]) = wlb;
        __syncthreads();
        if (it < 3) {  // prefetch next k-chunk (overlaps MFMA)
          xv  = *(const float4*)(x + (size_t)(row0 + xr) * KIN + (it + 1) * 64 + xc4);
          whb = *(const bf16x8*)(whT  + (size_t)wcol * KIN + (it + 1) * 64 + wc * 8);
          wlb = *(const bf16x8*)(wloT + (size_t)wcol * KIN + (it + 1) * 64 + wc * 8);
        }
#pragma unroll
        for (int kk = 0; kk < 2; ++kk) {
          const int kb = kk * 32 + (lane >> 4) * 8;
          const int ar = wm * 16 + (lane & 15);
          const bf16x8 ah = *(const bf16x8*)(&axh[ar * 72 + kb]);
          const bf16x8 al = *(const bf16x8*)(&axl[ar * 72 + kb]);
#pragma unroll
          for (int n = 0; n < 2; ++n) {
            const int cidx = wn * 32 + n * 16 + (lane & 15);
            const bf16x8 bh  = *(const bf16x8*)(&bwh[cidx * 72 + kb]);
            const bf16x8 blo = *(const bf16x8*)(&bwl[cidx * 72 + kb]);
            acc[n] = __builtin_amdgcn_mfma_f32_16x16x32_bf16(ah, bh,  acc[n], 0, 0, 0);
            acc[n] = __builtin_amdgcn_mfma_f32_16x16x32_bf16(ah, blo, acc[n], 0, 0, 0);
            acc[n] = __builtin_amdgcn_mfma_f32_16x16x32_bf16(al, bh,  acc[n], 0, 0, 0);
          }
        }
      }
      needSync = true;
      // epilogue: C map col=lane&15, row=(lane>>4)*4+r
      const int rb = row0 + wm * 16 + (lane >> 4) * 4;
      const int cb = wn * 32 + (lane & 15);
#pragma unroll
      for (int n = 0; n < 2; ++n)
#pragma unroll
        for (int r = 0; r < 4; ++r)
          feats[(size_t)(rb + r) * FO + cb + n * 16] = acc[n][r];
    }
  }
}

// ---------------- Kernel 3b: alpha/beta per sorted-j, kpos/E1/E2 per row ----
__global__ __launch_bounds__(512) void k3b_ab(const float* __restrict__ f1sort,
                                              const float* __restrict__ sc1,
                                              const float* __restrict__ sc2,
                                              const float* __restrict__ f2sort,
                                              const float* __restrict__ f1g,
                                              float* __restrict__ alphaS,
                                              float* __restrict__ betaS,
                                              int* __restrict__ kposA,
                                              float* __restrict__ E1g,
                                              float* __restrict__ E2g) {
  __shared__ float s_f1[NN];  // 16 KiB
  __shared__ float s_f2[NN];  // 16 KiB
  const int b = blockIdx.x >> 3;
  const int part = blockIdx.x & 7;
  const int base = b * NN;
  for (int i = threadIdx.x; i < NN; i += 512) {
    s_f1[i] = f1sort[base + i];
    s_f2[i] = f2sort[base + i];
  }
  __syncthreads();
  const int g = part * 512 + threadIdx.x;
  const float T1 = sc1[base + NN - 1];
  const float f1max = s_f1[NN - 1];
  {
    const float f2v = s_f2[g];
    const float m = f1max + f2v;
    const float M = (m >= 0.f) ? m : SLOPE * m;      // column max of leaky scores
    const int p = lower_bound_s(s_f1, NN, -f2v);     // first i with f1 >= -f2
    const float S1 = T1 - (p > 0 ? sc1[base + p - 1] : 0.f);
    const float S2 = (p > 0 ? sc2[base + p - 1] : 0.f);
    const float ea = expf(f2v - M);
    const float eb = expf(SLOPE * f2v - M);
    const float invD = 1.0f / (ea * S1 + eb * S2);
    alphaS[base + g] = ea * invD;
    betaS[base + g]  = eb * invD;
  }
  {
    const float f1v = f1g[base + g];
    kposA[base + g] = lower_bound_s(s_f2, NN, -f1v); // first sorted-j with f2 >= -f1
    E1g[base + g] = expf(f1v);
    E2g[base + g] = expf(SLOPE * f1v);
  }
}

// ---------------- Kernel 4a: per-position inclusive prefixes ----------------
__global__ __launch_bounds__(128) void k4a_pref(const float* __restrict__ feats,
                                                const float* __restrict__ alphaS,
                                                const float* __restrict__ betaS,
                                                const int* __restrict__ jidxS,
                                                float* __restrict__ finePreA,
                                                float* __restrict__ finePreB) {
  const int b = blockIdx.x >> 6, cc = blockIdx.x & 63;
  const int o = threadIdx.x;
  const int base = b * NN + cc * 64;
  const float* fb = feats + (size_t)b * NN * FO;
  float accA = 0.f, accB = 0.f;
#pragma unroll 8
  for (int q = 0; q < 64; ++q) {
    const int kk = base + q;
    const int j = jidxS[kk];
    const float fv = fb[(size_t)j * FO + o];
    accA = fmaf(alphaS[kk], fv, accA);
    accB = fmaf(betaS[kk], fv, accB);
    finePreA[(size_t)kk * FO + o] = accA;
    finePreB[(size_t)kk * FO + o] = accB;
  }
}

// ---------------- Kernel 4c: exclusive prefix over coarse sums --------------
__global__ __launch_bounds__(128) void k4c_coar(const float* __restrict__ finePreA,
                                                const float* __restrict__ finePreB,
                                                float* __restrict__ coarA,
                                                float* __restrict__ coarB) {
  const int b = blockIdx.x;
  const int o = threadIdx.x;
  float runA = 0.f, runB = 0.f;
#pragma unroll
  for (int c = 0; c < NCC; ++c) {
    coarA[(size_t)(b * (NCC + 1) + c) * FO + o] = runA;
    coarB[(size_t)(b * (NCC + 1) + c) * FO + o] = runB;
    runA += finePreA[(size_t)(b * NN + c * 64 + 63) * FO + o];
    runB += finePreB[(size_t)(b * NN + c * 64 + 63) * FO + o];
  }
  coarA[(size_t)(b * (NCC + 1) + NCC) * FO + o] = runA;   // total
  coarB[(size_t)(b * (NCC + 1) + NCC) * FO + o] = runB;
}

// ---------------- Kernel 5: streaming combine (no gathers) ------------------
__global__ __launch_bounds__(256) void k5_out(const float* __restrict__ finePreA,
                                              const float* __restrict__ finePreB,
                                              const float* __restrict__ coarA,
                                              const float* __restrict__ coarB,
                                              const int* __restrict__ kposA,
                                              const float* __restrict__ E1g,
                                              const float* __restrict__ E2g,
                                              float* __restrict__ out) {
  const int t = threadIdx.x;
  const int row = blockIdx.x * 2 + (t >> 7);
  const int o = t & 127;
  const int b = row >> 12;  // NN = 4096
  const int kp = kposA[row];
  const float e1 = E1g[row], e2 = E2g[row];
  const int c = kp >> 6;          // 0..64

  float runA = coarA[(size_t)(b * (NCC + 1) + c) * FO + o];
  float runB = coarB[(size_t)(b * (NCC + 1) + c) * FO + o];
  const float totA = coarA[(size_t)(b * (NCC + 1) + NCC) * FO + o];
  if (kp & 63) {
    runA += finePreA[(size_t)(b * NN + kp - 1) * FO + o];
    runB += finePreB[(size_t)(b * NN + kp - 1) * FO + o];
  }
  out[(size_t)row * FO + o] = fmaf(e1, totA - runA, e2 * runB);
}

extern "C" void kernel_launch(void* const* d_in, const int* in_sizes, int n_in,
                              void* d_out, int out_size, void* d_ws, size_t ws_size,
                              hipStream_t stream) {
  const float* x  = (const float*)d_in[0];
  const float* W  = (const float*)d_in[1];
  const float* wl = (const float*)d_in[2];
  const float* bl = (const float*)d_in[3];
  const float* wr = (const float*)d_in[4];
  const float* br = (const float*)d_in[5];
  float* out = (float*)d_out;

  float* ws = (float*)d_ws;
  float* feats    = ws; ws += NROW * FO;
  float* finePreA = ws; ws += NROW * FO;
  float* finePreB = ws; ws += NROW * FO;
  float* f1g      = ws; ws += NROW;
  float* f2g      = ws; ws += NROW;
  float* f1sort   = ws; ws += NROW;
  float* f2sort   = ws; ws += NROW;
  float* sc1      = ws; ws += NROW;
  float* sc2      = ws; ws += NROW;
  float* alphaS   = ws; ws += NROW;
  float* betaS    = ws; ws += NROW;
  float* E1g      = ws; ws += NROW;
  float* E2g      = ws; ws += NROW;
  int* jidxS      = (int*)ws; ws += NROW;
  int* kposA      = (int*)ws; ws += NROW;
  float* coarA    = ws; ws += NB * (NCC + 1) * FO;
  float* coarB    = ws; ws += NB * (NCC + 1) * FO;
  u16* whT  = (u16*)ws; ws += FO * KIN / 2;     // bf16 [128 col][256 k]
  u16* wloT = (u16*)ws; ws += FO * KIN / 2;
  (void)in_sizes; (void)n_in; (void)out_size; (void)ws_size;

  hipLaunchKernelGGL(k0_prep,  dim3(NROW / 64), dim3(256),  0, stream,
                     x, W, wl, bl, wr, br, whT, wloT, f1g, f2g);
  hipLaunchKernelGGL(kB_main,  dim3(256),       dim3(1024), 0, stream,
                     x, whT, wloT, f1g, f2g, feats,
                     f1sort, sc1, sc2, f2sort, jidxS);
  hipLaunchKernelGGL(k3b_ab,   dim3(NB * 8),    dim3(512),  0, stream,
                     f1sort, sc1, sc2, f2sort, f1g, alphaS, betaS, kposA, E1g, E2g);
  hipLaunchKernelGGL(k4a_pref, dim3(NB * NCC),  dim3(128),  0, stream,
                     feats, alphaS, betaS, jidxS, finePreA, finePreB);
  hipLaunchKernelGGL(k4c_coar, dim3(NB),        dim3(128),  0, stream,
                     finePreA, finePreB, coarA, coarB);
  hipLaunchKernelGGL(k5_out,   dim3(NROW / 2),  dim3(256),  0, stream,
                     finePreA, finePreB, coarA, coarB, kposA, E1g, E2g, out);
}